// Round 2
// baseline (807.578 us; speedup 1.0000x reference)
//
#include <hip/hip_runtime.h>
#include <hip/hip_bf16.h>
#include <stdint.h>

typedef unsigned short ushort_t;
typedef __attribute__((ext_vector_type(8))) short short8;
typedef __attribute__((ext_vector_type(4))) float f32x4;

__device__ __forceinline__ float b2f(ushort_t u) {
    union { uint32_t i; float f; } v; v.i = ((uint32_t)u) << 16; return v.f;
}
__device__ __forceinline__ ushort_t f2b(float f) {
    union { float f; uint32_t i; } v; v.f = f;
    uint32_t r = v.i + 0x7fff + ((v.i >> 16) & 1);
    return (ushort_t)(r >> 16);
}

// ---------------------------------------------------------------------------
// fp32 -> bf16 cast, vectorized (n must be a multiple of 4*256 per grid calc)
// ---------------------------------------------------------------------------
__global__ __launch_bounds__(256) void cast_f2b_kernel(
    const float4* __restrict__ in, ushort4* __restrict__ out, int n4)
{
    int g = blockIdx.x * 256 + threadIdx.x;
    if (g < n4) {
        float4 v = in[g];
        ushort4 o;
        o.x = f2b(v.x); o.y = f2b(v.y); o.z = f2b(v.z); o.w = f2b(v.w);
        out[g] = o;
    }
}

// ---------------------------------------------------------------------------
// bf16 GEMM: C[m,n] = sum_k A[m,k]*B[n,k]   (A,B bf16 row-major (M,K)/(N,K))
// BM=BN=128, BK=32, 256 threads = 4 waves in 2x2, each wave 64x64 (4x4 MFMA).
// EPI: 0 = fp32 store, 2 = fp32 softplus(x + bias[n]) store
// ---------------------------------------------------------------------------
#define BM 128
#define BN 128
#define BK 32

template <int EPI>
__global__ __launch_bounds__(256) void gemm_bt(
    const ushort_t* __restrict__ A, int lda,
    const ushort_t* __restrict__ B, int ldb,
    float* __restrict__ Cout, int ldc,
    const float* __restrict__ bias,
    int M, int N, int Kd)
{
    __shared__ ushort_t As[BM * BK];
    __shared__ ushort_t Bs[BN * BK];

    const int tid  = threadIdx.x;
    const int m0   = blockIdx.y * BM;
    const int n0   = blockIdx.x * BN;
    const int wave = tid >> 6;
    const int lane = tid & 63;
    const int wm   = (wave >> 1) * 64;
    const int wn   = (wave & 1) * 64;
    const int lr   = lane & 15;   // frag row / C col
    const int quad = lane >> 4;   // 0..3

    f32x4 acc[4][4];
#pragma unroll
    for (int i = 0; i < 4; i++)
#pragma unroll
        for (int j = 0; j < 4; j++) acc[i][j] = f32x4{0.f, 0.f, 0.f, 0.f};

    const int srow  = tid >> 1;            // 0..127
    const int scol8 = (tid & 1) * 2;       // units of 8 bf16

    for (int k0 = 0; k0 < Kd; k0 += BK) {
#pragma unroll
        for (int q = 0; q < 2; q++) {
            int c8 = scol8 + q;  // 0..3
            uint4 va = *(const uint4*)(A + (size_t)(m0 + srow) * lda + k0 + c8 * 8);
            *(uint4*)(&As[srow * BK + c8 * 8]) = va;
        }
#pragma unroll
        for (int q = 0; q < 2; q++) {
            int c8 = scol8 + q;
            int brow = n0 + srow;
            uint4 vb = make_uint4(0u, 0u, 0u, 0u);
            if (brow < N) vb = *(const uint4*)(B + (size_t)brow * ldb + k0 + c8 * 8);
            *(uint4*)(&Bs[srow * BK + c8 * 8]) = vb;
        }
        __syncthreads();

        short8 af[4], bf[4];
#pragma unroll
        for (int i = 0; i < 4; i++)
            af[i] = *(const short8*)(&As[(wm + i * 16 + lr) * BK + quad * 8]);
#pragma unroll
        for (int j = 0; j < 4; j++)
            bf[j] = *(const short8*)(&Bs[(wn + j * 16 + lr) * BK + quad * 8]);
#pragma unroll
        for (int i = 0; i < 4; i++)
#pragma unroll
            for (int j = 0; j < 4; j++)
                acc[i][j] = __builtin_amdgcn_mfma_f32_16x16x32_bf16(af[i], bf[j], acc[i][j], 0, 0, 0);
        __syncthreads();
    }

#pragma unroll
    for (int i = 0; i < 4; i++) {
        int m = m0 + wm + i * 16 + quad * 4;
#pragma unroll
        for (int j = 0; j < 4; j++) {
            int n = n0 + wn + j * 16 + lr;
            if (n < N) {
#pragma unroll
                for (int r = 0; r < 4; r++) {
                    float v = acc[i][j][r];
                    size_t off = (size_t)(m + r) * ldc + n;
                    if (EPI == 0) {
                        Cout[off] = v;
                    } else {
                        float x = v + bias[n];
                        float sp = (x > 20.f) ? x : log1pf(expf(x));
                        Cout[off] = sp;
                    }
                }
            }
        }
    }
}

// ---------------------------------------------------------------------------
// Causal depthwise conv (K=4) + bias + silu for both branches; fp32 in,
// bf16 out. Branch 1 uses the time-reversed sequence; outputs in branch-local
// coordinates [br][b][t][e].
// ---------------------------------------------------------------------------
__global__ __launch_bounds__(256) void conv_silu_kernel(
    const float* __restrict__ xz,
    const float* __restrict__ w_f, const float* __restrict__ cb_f,
    const float* __restrict__ w_b, const float* __restrict__ cb_b,
    ushort_t* __restrict__ xc16)
{
    int g = blockIdx.x * 256 + threadIdx.x;   // 2^23 total
    int e  = g & 2047;
    int t  = (g >> 11) & 511;
    int b  = (g >> 20) & 3;
    int br = g >> 22;

    const float* w  = br ? w_b  : w_f;
    const float* cb = br ? cb_b : cb_f;

    float acc = cb[e];
    float4 wv = *(const float4*)(w + e * 4);
    float wk[4] = { wv.x, wv.y, wv.z, wv.w };

#pragma unroll
    for (int k = 0; k < 4; k++) {
        int tp = t - 3 + k;
        if (tp >= 0) {
            int row = br ? (511 - tp) : tp;
            float u = xz[((size_t)(b * 512 + row)) * 4096 + e];
            acc += wk[k] * u;
        }
    }
    float s = acc / (1.f + __expf(-acc));
    xc16[g] = f2b(s);
}

// ---------------------------------------------------------------------------
// Selective scan + gating. Lane layout: n = tid&15, e_local = tid>>4.
// Block handles (branch, b, 16 e's); serial over t; y reduced over n by
// shfl_xor; gated bf16 output written by n==0 lanes.
// ---------------------------------------------------------------------------
__global__ __launch_bounds__(256) void scan_kernel(
    const float* __restrict__ delta,      // [2][B][L][ED] fp32
    const ushort_t* __restrict__ xc,      // [2][B][L][ED] bf16
    const float* __restrict__ dbc,        // [2][B][L][96] fp32
    const float* __restrict__ xz,         // [B][L][4096] fp32 (z part)
    const float* __restrict__ Alog_f, const float* __restrict__ Alog_b,
    const float* __restrict__ Dp_f,   const float* __restrict__ Dp_b,
    ushort_t* __restrict__ yf, ushort_t* __restrict__ yb)
{
    int tid = threadIdx.x;
    int n  = tid & 15;
    int el = tid >> 4;
    int blk = blockIdx.x;              // 1024
    int e  = (blk & 127) * 16 + el;
    int b  = (blk >> 7) & 3;
    int br = blk >> 9;

    const float* Alog = br ? Alog_b : Alog_f;
    const float* Dpp  = br ? Dp_b   : Dp_f;
    float A = -__expf(Alog[e * 16 + n]);
    float D = Dpp[e];

    size_t base = ((size_t)br * 4 * 512 + (size_t)b * 512);
    const float*    dlt  = delta + base * 2048;
    const ushort_t* xcb  = xc    + base * 2048;
    const float*    dbcb = dbc   + base * 96;
    ushort_t* y = (br ? yb : yf) + (size_t)b * 512 * 2048;

    float h = 0.f;
    for (int t = 0; t < 512; t++) {
        float d  = dlt[(size_t)t * 2048 + e];
        float xv = b2f(xcb[(size_t)t * 2048 + e]);
        float Bv = dbcb[t * 96 + 64 + n];
        float Cv = dbcb[t * 96 + 80 + n];
        h = __expf(d * A) * h + d * Bv * xv;
        float p = h * Cv;
        p += __shfl_xor(p, 1);
        p += __shfl_xor(p, 2);
        p += __shfl_xor(p, 4);
        p += __shfl_xor(p, 8);
        if (n == 0) {
            int torig = br ? (511 - t) : t;
            float zv = xz[((size_t)(b * 512 + torig)) * 4096 + 2048 + e];
            float g = (p + D * xv) * (zv / (1.f + __expf(-zv)));
            y[(size_t)t * 2048 + e] = f2b(g);
        }
    }
}

__global__ __launch_bounds__(256) void combine_kernel(
    const ushort_t* __restrict__ yf, const ushort_t* __restrict__ yb,
    ushort_t* __restrict__ yc)
{
    int g = blockIdx.x * 256 + threadIdx.x;   // 2^22
    int e = g & 2047;
    int t = (g >> 11) & 511;
    int b = g >> 20;
    float a = b2f(yf[g]);
    float c = b2f(yb[((size_t)(b * 512 + (511 - t))) * 2048 + e]);
    yc[g] = f2b(0.5f * (a + c));
}

// ---------------------------------------------------------------------------
// Workspace layout (bytes), all offsets 4KB-multiples
// ---------------------------------------------------------------------------
static const size_t TT = 2048;  // B_SZ * L
static const size_t OFF_XZ    = 0;                          // T*4096 f32   32MB
static const size_t OFF_XC16  = OFF_XZ    + TT*4096*4;      // 2*T*2048 bf16 16MB
static const size_t OFF_DBC   = OFF_XC16  + 2*TT*2048*2;    // 2*T*96 f32   1.5MB
static const size_t OFF_DBC16 = OFF_DBC   + 2*TT*96*4;      // 2*T*96 bf16  .75MB
static const size_t OFF_DELTA = OFF_DBC16 + 2*TT*96*2;      // 2*T*2048 f32 32MB
static const size_t OFF_YF    = OFF_DELTA + 2*TT*2048*4;    // T*2048 bf16  8MB
static const size_t OFF_YB    = OFF_YF    + TT*2048*2;      // T*2048 bf16  8MB
static const size_t OFF_YC16  = OFF_YB    + TT*2048*2;      // T*2048 bf16  8MB
static const size_t OFF_X16   = OFF_YC16  + TT*2048*2;      // T*1024 bf16  4MB
static const size_t OFF_WIN16 = OFF_X16   + TT*1024*2;      // 4096*1024    8MB
static const size_t OFF_WX16  = OFF_WIN16 + 4096*1024*2;    // 2*96*2048    .75MB
static const size_t OFF_WDT16 = OFF_WX16  + 2*96*2048*2;    // 2*2048*64    .5MB
static const size_t OFF_WOUT16= OFF_WDT16 + 2*2048*64*2;    // 1024*2048    4MB
// total ~124MB

extern "C" void kernel_launch(void* const* d_in, const int* in_sizes, int n_in,
                              void* d_out, int out_size, void* d_ws, size_t ws_size,
                              hipStream_t stream) {
    const float* x       = (const float*)d_in[0];
    const float* W_in    = (const float*)d_in[1];
    const float* conv_w  = (const float*)d_in[2];
    const float* conv_b  = (const float*)d_in[3];
    const float* Wx      = (const float*)d_in[4];
    const float* Wdt     = (const float*)d_in[5];
    const float* b_dt    = (const float*)d_in[6];
    const float* A_log   = (const float*)d_in[7];
    const float* Dp      = (const float*)d_in[8];
    const float* conv_w_b= (const float*)d_in[9];
    const float* conv_b_b= (const float*)d_in[10];
    const float* Wx_b    = (const float*)d_in[11];
    const float* Wdt_b   = (const float*)d_in[12];
    const float* b_dt_b  = (const float*)d_in[13];
    const float* A_log_b = (const float*)d_in[14];
    const float* Dp_b    = (const float*)d_in[15];
    const float* W_out   = (const float*)d_in[16];
    float* out = (float*)d_out;

    char* ws = (char*)d_ws;
    float*    xz    = (float*)(ws + OFF_XZ);
    ushort_t* xc16  = (ushort_t*)(ws + OFF_XC16);
    float*    dbc   = (float*)(ws + OFF_DBC);
    ushort_t* dbc16 = (ushort_t*)(ws + OFF_DBC16);
    float*    delta = (float*)(ws + OFF_DELTA);
    ushort_t* yf    = (ushort_t*)(ws + OFF_YF);
    ushort_t* yb    = (ushort_t*)(ws + OFF_YB);
    ushort_t* yc16  = (ushort_t*)(ws + OFF_YC16);
    ushort_t* x16   = (ushort_t*)(ws + OFF_X16);
    ushort_t* win16 = (ushort_t*)(ws + OFF_WIN16);
    ushort_t* wx16  = (ushort_t*)(ws + OFF_WX16);
    ushort_t* wdt16 = (ushort_t*)(ws + OFF_WDT16);
    ushort_t* wout16= (ushort_t*)(ws + OFF_WOUT16);

    dim3 blk(256);

    // casts fp32 -> bf16 for GEMM operands
    cast_f2b_kernel<<<2048, blk, 0, stream>>>((const float4*)x,     (ushort4*)x16,    2048*1024/4);
    cast_f2b_kernel<<<4096, blk, 0, stream>>>((const float4*)W_in,  (ushort4*)win16,  4096*1024/4);
    cast_f2b_kernel<<<192,  blk, 0, stream>>>((const float4*)Wx,    (ushort4*)wx16,   96*2048/4);
    cast_f2b_kernel<<<192,  blk, 0, stream>>>((const float4*)Wx_b,  (ushort4*)(wx16 + 96*2048), 96*2048/4);
    cast_f2b_kernel<<<128,  blk, 0, stream>>>((const float4*)Wdt,   (ushort4*)wdt16,  2048*64/4);
    cast_f2b_kernel<<<128,  blk, 0, stream>>>((const float4*)Wdt_b, (ushort4*)(wdt16 + 2048*64), 2048*64/4);
    cast_f2b_kernel<<<2048, blk, 0, stream>>>((const float4*)W_out, (ushort4*)wout16, 1024*2048/4);

    // G1: xz = x @ W_in^T   (2048 x 4096, K=1024)
    gemm_bt<0><<<dim3(4096 / BN, 2048 / BM), blk, 0, stream>>>(
        x16, 1024, win16, 1024, xz, 4096, nullptr, 2048, 4096, 1024);

    // conv + silu, both branches -> bf16 x
    conv_silu_kernel<<<32768, blk, 0, stream>>>(
        xz, conv_w, conv_b, conv_w_b, conv_b_b, xc16);

    // G2: dbc = xc @ Wx^T per branch  (2048 x 96, K=2048), fp32 out
    gemm_bt<0><<<dim3(1, 16), blk, 0, stream>>>(
        xc16, 2048, wx16, 2048, dbc, 96, nullptr, 2048, 96, 2048);
    gemm_bt<0><<<dim3(1, 16), blk, 0, stream>>>(
        xc16 + TT * 2048, 2048, wx16 + 96*2048, 2048, dbc + TT * 96, 96, nullptr, 2048, 96, 2048);

    // cast dbc -> bf16 for the delta GEMM
    cast_f2b_kernel<<<384, blk, 0, stream>>>((const float4*)dbc, (ushort4*)dbc16, 2*2048*96/4);

    // G3: delta = softplus(dbc[:, :64] @ Wdt^T + b_dt) per branch (2048 x 2048, K=64)
    gemm_bt<2><<<dim3(2048 / BN, 16), blk, 0, stream>>>(
        dbc16, 96, wdt16, 64, delta, 2048, b_dt, 2048, 2048, 64);
    gemm_bt<2><<<dim3(2048 / BN, 16), blk, 0, stream>>>(
        dbc16 + TT * 96, 96, wdt16 + 2048*64, 64, delta + TT * 2048, 2048, b_dt_b, 2048, 2048, 64);

    // selective scan + gating, both branches -> bf16 y
    scan_kernel<<<1024, blk, 0, stream>>>(
        delta, xc16, dbc, xz, A_log, A_log_b, Dp, Dp_b, yf, yb);

    // combine fwd + reversed bwd
    combine_kernel<<<16384, blk, 0, stream>>>(yf, yb, yc16);

    // G4: out = y_comb @ W_out^T  (2048 x 1024, K=2048), fp32 out
    gemm_bt<0><<<dim3(1024 / BN, 16), blk, 0, stream>>>(
        yc16, 2048, wout16, 2048, out, 1024, nullptr, 2048, 1024, 2048);
}

// Round 3
// 403.852 us; speedup vs baseline: 1.9997x; 1.9997x over previous
//
#include <hip/hip_runtime.h>
#include <hip/hip_bf16.h>
#include <stdint.h>

typedef unsigned short ushort_t;
typedef __attribute__((ext_vector_type(8))) short short8;
typedef __attribute__((ext_vector_type(4))) float f32x4;

__device__ __forceinline__ float b2f(ushort_t u) {
    union { uint32_t i; float f; } v; v.i = ((uint32_t)u) << 16; return v.f;
}
__device__ __forceinline__ ushort_t f2b(float f) {
    union { float f; uint32_t i; } v; v.f = f;
    uint32_t r = v.i + 0x7fff + ((v.i >> 16) & 1);
    return (ushort_t)(r >> 16);
}

// ---------------------------------------------------------------------------
// Fused multi-tensor fp32 -> bf16 cast (7 segments, 1 launch)
// ---------------------------------------------------------------------------
struct CastSeg { const float4* src; ushort4* dst; };
struct CastArgs { CastSeg seg[7]; int start[8]; };

__global__ __launch_bounds__(256) void cast_multi(CastArgs a)
{
    int g = blockIdx.x * 256 + threadIdx.x;
    if (g >= a.start[7]) return;
    int s = 0;
#pragma unroll
    for (int i = 1; i < 7; i++) s += (g >= a.start[i]);
    int i = g - a.start[s];
    float4 v = a.seg[s].src[i];
    ushort4 o;
    o.x = f2b(v.x); o.y = f2b(v.y); o.z = f2b(v.z); o.w = f2b(v.w);
    a.seg[s].dst[i] = o;
}

// ---------------------------------------------------------------------------
// bf16 GEMM: C[m,n] = sum_k A[m,k]*B[n,k]. BM=BN=128, BK=32, 4 waves 2x2.
// Used for G1 (x@W_in^T) and G4 (y@W_out^T); M,N multiples of 128.
// ---------------------------------------------------------------------------
#define BM 128
#define BN 128
#define BK 32

template <int EPI>
__global__ __launch_bounds__(256) void gemm_bt(
    const ushort_t* __restrict__ A, int lda,
    const ushort_t* __restrict__ B, int ldb,
    float* __restrict__ Cout, int ldc, int Kd)
{
    __shared__ ushort_t As[BM * BK];
    __shared__ ushort_t Bs[BN * BK];

    const int tid  = threadIdx.x;
    const int m0   = blockIdx.y * BM;
    const int n0   = blockIdx.x * BN;
    const int wave = tid >> 6;
    const int lane = tid & 63;
    const int wm   = (wave >> 1) * 64;
    const int wn   = (wave & 1) * 64;
    const int lr   = lane & 15;
    const int quad = lane >> 4;

    f32x4 acc[4][4];
#pragma unroll
    for (int i = 0; i < 4; i++)
#pragma unroll
        for (int j = 0; j < 4; j++) acc[i][j] = f32x4{0.f, 0.f, 0.f, 0.f};

    const int srow  = tid >> 1;
    const int scol8 = (tid & 1) * 2;

    for (int k0 = 0; k0 < Kd; k0 += BK) {
#pragma unroll
        for (int q = 0; q < 2; q++) {
            int c8 = scol8 + q;
            *(uint4*)(&As[srow * BK + c8 * 8]) =
                *(const uint4*)(A + (size_t)(m0 + srow) * lda + k0 + c8 * 8);
        }
#pragma unroll
        for (int q = 0; q < 2; q++) {
            int c8 = scol8 + q;
            *(uint4*)(&Bs[srow * BK + c8 * 8]) =
                *(const uint4*)(B + (size_t)(n0 + srow) * ldb + k0 + c8 * 8);
        }
        __syncthreads();

        short8 af[4], bf[4];
#pragma unroll
        for (int i = 0; i < 4; i++)
            af[i] = *(const short8*)(&As[(wm + i * 16 + lr) * BK + quad * 8]);
#pragma unroll
        for (int j = 0; j < 4; j++)
            bf[j] = *(const short8*)(&Bs[(wn + j * 16 + lr) * BK + quad * 8]);
#pragma unroll
        for (int i = 0; i < 4; i++)
#pragma unroll
            for (int j = 0; j < 4; j++)
                acc[i][j] = __builtin_amdgcn_mfma_f32_16x16x32_bf16(af[i], bf[j], acc[i][j], 0, 0, 0);
        __syncthreads();
    }

#pragma unroll
    for (int i = 0; i < 4; i++) {
        int m = m0 + wm + i * 16 + quad * 4;
#pragma unroll
        for (int j = 0; j < 4; j++) {
            int n = n0 + wn + j * 16 + lr;
#pragma unroll
            for (int r = 0; r < 4; r++)
                Cout[(size_t)(m + r) * ldc + n] = acc[i][j][r];
        }
    }
}

// ---------------------------------------------------------------------------
// G2: dbc partials. grid (SK=4, M/128=16, br=2). A=xc16[br], B=wx16[br] (N=96)
// ---------------------------------------------------------------------------
__global__ __launch_bounds__(256) void gemm_g2(
    const ushort_t* __restrict__ xc, const ushort_t* __restrict__ wx,
    float* __restrict__ part)
{
    __shared__ ushort_t As[BM * BK];
    __shared__ ushort_t Bs[BN * BK];

    const int sk = blockIdx.x, mb = blockIdx.y, br = blockIdx.z;
    const ushort_t* A = xc + (size_t)br * 2048 * 2048;
    const ushort_t* B = wx + (size_t)br * 96 * 2048;
    float* C = part + (size_t)(sk * 2 + br) * 2048 * 96;
    const int m0 = mb * BM;
    const int kb = sk * 512;

    const int tid  = threadIdx.x;
    const int wave = tid >> 6;
    const int lane = tid & 63;
    const int wm   = (wave >> 1) * 64;
    const int wn   = (wave & 1) * 64;
    const int lr   = lane & 15;
    const int quad = lane >> 4;

    f32x4 acc[4][4];
#pragma unroll
    for (int i = 0; i < 4; i++)
#pragma unroll
        for (int j = 0; j < 4; j++) acc[i][j] = f32x4{0.f, 0.f, 0.f, 0.f};

    const int srow  = tid >> 1;
    const int scol8 = (tid & 1) * 2;

    for (int k0 = kb; k0 < kb + 512; k0 += BK) {
#pragma unroll
        for (int q = 0; q < 2; q++) {
            int c8 = scol8 + q;
            *(uint4*)(&As[srow * BK + c8 * 8]) =
                *(const uint4*)(A + (size_t)(m0 + srow) * 2048 + k0 + c8 * 8);
        }
#pragma unroll
        for (int q = 0; q < 2; q++) {
            int c8 = scol8 + q;
            uint4 vb = make_uint4(0u, 0u, 0u, 0u);
            if (srow < 96) vb = *(const uint4*)(B + (size_t)srow * 2048 + k0 + c8 * 8);
            *(uint4*)(&Bs[srow * BK + c8 * 8]) = vb;
        }
        __syncthreads();

        short8 af[4], bf[4];
#pragma unroll
        for (int i = 0; i < 4; i++)
            af[i] = *(const short8*)(&As[(wm + i * 16 + lr) * BK + quad * 8]);
#pragma unroll
        for (int j = 0; j < 4; j++)
            bf[j] = *(const short8*)(&Bs[(wn + j * 16 + lr) * BK + quad * 8]);
#pragma unroll
        for (int i = 0; i < 4; i++)
#pragma unroll
            for (int j = 0; j < 4; j++)
                acc[i][j] = __builtin_amdgcn_mfma_f32_16x16x32_bf16(af[i], bf[j], acc[i][j], 0, 0, 0);
        __syncthreads();
    }

#pragma unroll
    for (int i = 0; i < 4; i++) {
        int m = m0 + wm + i * 16 + quad * 4;
#pragma unroll
        for (int j = 0; j < 4; j++) {
            int n = wn + j * 16 + lr;
            if (n < 96) {
#pragma unroll
                for (int r = 0; r < 4; r++)
                    C[(size_t)(m + r) * 96 + n] = acc[i][j][r];
            }
        }
    }
}

__global__ __launch_bounds__(256) void reduce_dbc(
    const float4* __restrict__ part, float4* __restrict__ dbc,
    ushort4* __restrict__ dbc16)
{
    int g = blockIdx.x * 256 + threadIdx.x;   // 98304 total
    const int S = 2 * 2048 * 96 / 4;
    float4 a = part[g], b = part[g + S], c = part[g + 2 * S], d = part[g + 3 * S];
    float4 r; r.x = a.x + b.x + c.x + d.x; r.y = a.y + b.y + c.y + d.y;
    r.z = a.z + b.z + c.z + d.z; r.w = a.w + b.w + c.w + d.w;
    dbc[g] = r;
    ushort4 o; o.x = f2b(r.x); o.y = f2b(r.y); o.z = f2b(r.z); o.w = f2b(r.w);
    dbc16[g] = o;
}

// ---------------------------------------------------------------------------
// G3: delta = softplus(dbc[:, :64] @ Wdt^T + b_dt), both branches via grid z.
// ---------------------------------------------------------------------------
__global__ __launch_bounds__(256) void gemm_g3(
    const ushort_t* __restrict__ dbc16, const ushort_t* __restrict__ wdt,
    float* __restrict__ delta,
    const float* __restrict__ bdt_f, const float* __restrict__ bdt_b)
{
    __shared__ ushort_t As[BM * BK];
    __shared__ ushort_t Bs[BN * BK];

    const int br = blockIdx.z;
    const ushort_t* A = dbc16 + (size_t)br * 2048 * 96;
    const ushort_t* B = wdt + (size_t)br * 2048 * 64;
    float* C = delta + (size_t)br * 2048 * 2048;
    const float* bias = br ? bdt_b : bdt_f;

    const int tid  = threadIdx.x;
    const int m0   = blockIdx.y * BM;
    const int n0   = blockIdx.x * BN;
    const int wave = tid >> 6;
    const int lane = tid & 63;
    const int wm   = (wave >> 1) * 64;
    const int wn   = (wave & 1) * 64;
    const int lr   = lane & 15;
    const int quad = lane >> 4;

    f32x4 acc[4][4];
#pragma unroll
    for (int i = 0; i < 4; i++)
#pragma unroll
        for (int j = 0; j < 4; j++) acc[i][j] = f32x4{0.f, 0.f, 0.f, 0.f};

    const int srow  = tid >> 1;
    const int scol8 = (tid & 1) * 2;

    for (int k0 = 0; k0 < 64; k0 += BK) {
#pragma unroll
        for (int q = 0; q < 2; q++) {
            int c8 = scol8 + q;
            *(uint4*)(&As[srow * BK + c8 * 8]) =
                *(const uint4*)(A + (size_t)(m0 + srow) * 96 + k0 + c8 * 8);
        }
#pragma unroll
        for (int q = 0; q < 2; q++) {
            int c8 = scol8 + q;
            *(uint4*)(&Bs[srow * BK + c8 * 8]) =
                *(const uint4*)(B + (size_t)(n0 + srow) * 64 + k0 + c8 * 8);
        }
        __syncthreads();

        short8 af[4], bf[4];
#pragma unroll
        for (int i = 0; i < 4; i++)
            af[i] = *(const short8*)(&As[(wm + i * 16 + lr) * BK + quad * 8]);
#pragma unroll
        for (int j = 0; j < 4; j++)
            bf[j] = *(const short8*)(&Bs[(wn + j * 16 + lr) * BK + quad * 8]);
#pragma unroll
        for (int i = 0; i < 4; i++)
#pragma unroll
            for (int j = 0; j < 4; j++)
                acc[i][j] = __builtin_amdgcn_mfma_f32_16x16x32_bf16(af[i], bf[j], acc[i][j], 0, 0, 0);
        __syncthreads();
    }

#pragma unroll
    for (int i = 0; i < 4; i++) {
        int m = m0 + wm + i * 16 + quad * 4;
#pragma unroll
        for (int j = 0; j < 4; j++) {
            int n = n0 + wn + j * 16 + lr;
            float bn = bias[n];
#pragma unroll
            for (int r = 0; r < 4; r++) {
                float x = acc[i][j][r] + bn;
                C[(size_t)(m + r) * 2048 + n] = (x > 20.f) ? x : log1pf(expf(x));
            }
        }
    }
}

// ---------------------------------------------------------------------------
// Causal depthwise conv (K=4) + bias + silu, both branches, bf16 out.
// ---------------------------------------------------------------------------
__global__ __launch_bounds__(256) void conv_silu_kernel(
    const float* __restrict__ xz,
    const float* __restrict__ w_f, const float* __restrict__ cb_f,
    const float* __restrict__ w_b, const float* __restrict__ cb_b,
    ushort_t* __restrict__ xc16)
{
    int g = blockIdx.x * 256 + threadIdx.x;
    int e  = g & 2047;
    int t  = (g >> 11) & 511;
    int b  = (g >> 20) & 3;
    int br = g >> 22;

    const float* w  = br ? w_b  : w_f;
    const float* cb = br ? cb_b : cb_f;

    float acc = cb[e];
    float4 wv = *(const float4*)(w + e * 4);
    float wk[4] = { wv.x, wv.y, wv.z, wv.w };

#pragma unroll
    for (int k = 0; k < 4; k++) {
        int tp = t - 3 + k;
        if (tp >= 0) {
            int row = br ? (511 - tp) : tp;
            acc += wk[k] * xz[((size_t)(b * 512 + row)) * 4096 + e];
        }
    }
    float s = acc / (1.f + __expf(-acc));
    xc16[g] = f2b(s);
}

// ---------------------------------------------------------------------------
// Selective scan v2: 256 blocks, block = (br, b, 64 e). Thread owns 4 states.
// LDS double-buffered 64-t chunks with register prefetch; gating in flush.
// ---------------------------------------------------------------------------
__global__ __launch_bounds__(256) void scan_kernel(
    const float* __restrict__ delta,      // [2][B][L][ED] fp32
    const ushort_t* __restrict__ xc,      // [2][B][L][ED] bf16
    const float* __restrict__ dbc,        // [2][B][L][96] fp32
    const float* __restrict__ xz,         // [B][L][4096] fp32 (z half)
    const float* __restrict__ Alog_f, const float* __restrict__ Alog_b,
    const float* __restrict__ Dp_f,   const float* __restrict__ Dp_b,
    ushort_t* __restrict__ yf, ushort_t* __restrict__ yb)
{
    const int blk = blockIdx.x;            // 0..255
    const int eg = blk & 31;               // 32 e-groups of 64
    const int b  = (blk >> 5) & 3;
    const int br = blk >> 7;
    const int e0 = eg * 64;

    const int tid = threadIdx.x;
    const int ng  = tid & 3;               // n = ng*4 + j
    const int el  = tid >> 2;              // 0..63
    const int e   = e0 + el;

    const float* Alog = br ? Alog_b : Alog_f;
    const float* Dpp  = br ? Dp_b   : Dp_f;
    float4 Av = *(const float4*)(Alog + e * 16 + ng * 4);
    float A0 = -__expf(Av.x), A1 = -__expf(Av.y), A2 = -__expf(Av.z), A3 = -__expf(Av.w);

    size_t tb = ((size_t)br * 4 + b) * 512;
    const float*    dlt  = delta + tb * 2048;
    const ushort_t* xcb  = xc    + tb * 2048;
    const float*    dbcb = dbc   + tb * 96;
    ushort_t* y = (br ? yb : yf) + (size_t)b * 512 * 2048;

    __shared__ float    sd[2][64][64];
    __shared__ ushort_t sx[2][64][64];
    __shared__ float    sB[2][64][16];
    __shared__ float    sC[2][64][16];
    __shared__ float    sy[64][64];

    // staging / flush assignment: thread -> (row stt, 16-elem col sc16)
    const int stt  = tid >> 2;             // 0..63
    const int sc16 = (tid & 3) * 16;
    const int scd8 = (tid & 3) * 8;        // dbc dword col: 0,8,16,24

    float4 rD[4];
#pragma unroll
    for (int q = 0; q < 4; q++) rD[q] = *(const float4*)(Dpp + e0 + sc16 + 4 * q);

    float4 rd[4]; uint4 rx[2]; float4 rbc[2];

    auto load_regs = [&](int c) {
        int t0 = c * 64;
        const float* dsrc = dlt + (size_t)(t0 + stt) * 2048 + e0 + sc16;
#pragma unroll
        for (int k = 0; k < 4; k++) rd[k] = *(const float4*)(dsrc + 4 * k);
        const ushort_t* xsrc = xcb + (size_t)(t0 + stt) * 2048 + e0 + sc16;
#pragma unroll
        for (int k = 0; k < 2; k++) rx[k] = *(const uint4*)(xsrc + 8 * k);
        const float* bsrc = dbcb + (size_t)(t0 + stt) * 96 + 64 + scd8;
#pragma unroll
        for (int k = 0; k < 2; k++) rbc[k] = *(const float4*)(bsrc + 4 * k);
    };
    auto write_lds = [&](int buf) {
#pragma unroll
        for (int k = 0; k < 4; k++) *(float4*)(&sd[buf][stt][sc16 + 4 * k]) = rd[k];
#pragma unroll
        for (int k = 0; k < 2; k++) *(uint4*)(&sx[buf][stt][sc16 + 8 * k]) = rx[k];
        if (scd8 < 16) {
            *(float4*)(&sB[buf][stt][scd8])     = rbc[0];
            *(float4*)(&sB[buf][stt][scd8 + 4]) = rbc[1];
        } else {
            *(float4*)(&sC[buf][stt][scd8 - 16])     = rbc[0];
            *(float4*)(&sC[buf][stt][scd8 - 12])     = rbc[1];
        }
    };

    float h0 = 0.f, h1 = 0.f, h2 = 0.f, h3 = 0.f;

    load_regs(0);
    write_lds(0);
    for (int c = 0; c < 8; ++c) {
        if (c < 7) load_regs(c + 1);
        __syncthreads();
        const int buf = c & 1;
#pragma unroll 4
        for (int t = 0; t < 64; ++t) {
            float d  = sd[buf][t][el];
            float xv = b2f(sx[buf][t][el]);
            float4 Bv = *(const float4*)(&sB[buf][t][ng * 4]);
            float4 Cv = *(const float4*)(&sC[buf][t][ng * 4]);
            float dx = d * xv;
            h0 = __expf(d * A0) * h0 + dx * Bv.x;
            h1 = __expf(d * A1) * h1 + dx * Bv.y;
            h2 = __expf(d * A2) * h2 + dx * Bv.z;
            h3 = __expf(d * A3) * h3 + dx * Bv.w;
            float p = h0 * Cv.x + h1 * Cv.y + h2 * Cv.z + h3 * Cv.w;
            p += __shfl_xor(p, 1);
            p += __shfl_xor(p, 2);
            if (ng == 0) sy[t][el] = p;
        }
        __syncthreads();
        // flush: gate with z*silu + D*x, store bf16 (coalesced)
        {
            int row  = c * 64 + stt;
            int orow = br ? (511 - row) : row;
            const float* zsrc = xz + ((size_t)(b * 512 + orow)) * 4096 + 2048 + e0 + sc16;
            ushort_t* ydst = y + (size_t)row * 2048 + e0 + sc16;
            uint32_t op[8];
#pragma unroll
            for (int q = 0; q < 4; q++) {
                float4 pv = *(const float4*)(&sy[stt][sc16 + 4 * q]);
                uint2 xr = *(const uint2*)(&sx[buf][stt][sc16 + 4 * q]);
                float xv0 = b2f(xr.x & 0xffff), xv1 = b2f(xr.x >> 16);
                float xv2 = b2f(xr.y & 0xffff), xv3 = b2f(xr.y >> 16);
                float4 zv = *(const float4*)(zsrc + 4 * q);
                float4 Dv = rD[q];
                float g0 = (pv.x + Dv.x * xv0) * (zv.x / (1.f + __expf(-zv.x)));
                float g1 = (pv.y + Dv.y * xv1) * (zv.y / (1.f + __expf(-zv.y)));
                float g2 = (pv.z + Dv.z * xv2) * (zv.z / (1.f + __expf(-zv.z)));
                float g3 = (pv.w + Dv.w * xv3) * (zv.w / (1.f + __expf(-zv.w)));
                op[2 * q]     = (uint32_t)f2b(g0) | ((uint32_t)f2b(g1) << 16);
                op[2 * q + 1] = (uint32_t)f2b(g2) | ((uint32_t)f2b(g3) << 16);
            }
            *(uint4*)(ydst)     = make_uint4(op[0], op[1], op[2], op[3]);
            *(uint4*)(ydst + 8) = make_uint4(op[4], op[5], op[6], op[7]);
        }
        if (c < 7) write_lds((c + 1) & 1);
    }
}

__global__ __launch_bounds__(256) void combine_kernel(
    const uint2* __restrict__ yf, const uint2* __restrict__ yb,
    uint2* __restrict__ yc)
{
    int g = blockIdx.x * 256 + threadIdx.x;   // 1048576 total
    int e4 = g & 511;
    int t  = (g >> 9) & 511;
    int b  = g >> 18;
    uint2 a = yf[g];
    uint2 c = yb[((size_t)(b * 512 + 511 - t)) * 512 + e4];
    uint2 o;
    o.x = (uint32_t)f2b(0.5f * (b2f(a.x & 0xffff) + b2f(c.x & 0xffff))) |
          ((uint32_t)f2b(0.5f * (b2f(a.x >> 16) + b2f(c.x >> 16))) << 16);
    o.y = (uint32_t)f2b(0.5f * (b2f(a.y & 0xffff) + b2f(c.y & 0xffff))) |
          ((uint32_t)f2b(0.5f * (b2f(a.y >> 16) + b2f(c.y >> 16))) << 16);
    yc[g] = o;
}

// ---------------------------------------------------------------------------
// Workspace layout (bytes)
// ---------------------------------------------------------------------------
static const size_t TT = 2048;  // B_SZ * L
static const size_t OFF_XZ    = 0;                          // 32MB
static const size_t OFF_XC16  = OFF_XZ    + TT*4096*4;      // 16MB
static const size_t OFF_DBC   = OFF_XC16  + 2*TT*2048*2;    // 1.5MB
static const size_t OFF_DBC16 = OFF_DBC   + 2*TT*96*4;      // .75MB
static const size_t OFF_DELTA = OFF_DBC16 + 2*TT*96*2;      // 32MB
static const size_t OFF_YF    = OFF_DELTA + 2*TT*2048*4;    // 8MB
static const size_t OFF_YB    = OFF_YF    + TT*2048*2;      // 8MB
static const size_t OFF_YC16  = OFF_YB    + TT*2048*2;      // 8MB
static const size_t OFF_X16   = OFF_YC16  + TT*2048*2;      // 4MB
static const size_t OFF_WIN16 = OFF_X16   + TT*1024*2;      // 8MB
static const size_t OFF_WX16  = OFF_WIN16 + 4096*1024*2;    // .75MB
static const size_t OFF_WDT16 = OFF_WX16  + 2*96*2048*2;    // .5MB
static const size_t OFF_WOUT16= OFF_WDT16 + 2*2048*64*2;    // 4MB
static const size_t OFF_PART  = OFF_WOUT16+ 1024*2048*2;    // 6MB
// total ~130MB

extern "C" void kernel_launch(void* const* d_in, const int* in_sizes, int n_in,
                              void* d_out, int out_size, void* d_ws, size_t ws_size,
                              hipStream_t stream) {
    const float* x       = (const float*)d_in[0];
    const float* W_in    = (const float*)d_in[1];
    const float* conv_w  = (const float*)d_in[2];
    const float* conv_b  = (const float*)d_in[3];
    const float* Wx      = (const float*)d_in[4];
    const float* Wdt     = (const float*)d_in[5];
    const float* b_dt    = (const float*)d_in[6];
    const float* A_log   = (const float*)d_in[7];
    const float* Dp      = (const float*)d_in[8];
    const float* conv_w_b= (const float*)d_in[9];
    const float* conv_b_b= (const float*)d_in[10];
    const float* Wx_b    = (const float*)d_in[11];
    const float* Wdt_b   = (const float*)d_in[12];
    const float* b_dt_b  = (const float*)d_in[13];
    const float* A_log_b = (const float*)d_in[14];
    const float* Dp_b    = (const float*)d_in[15];
    const float* W_out   = (const float*)d_in[16];
    float* out = (float*)d_out;

    char* ws = (char*)d_ws;
    float*    xz    = (float*)(ws + OFF_XZ);
    ushort_t* xc16  = (ushort_t*)(ws + OFF_XC16);
    float*    dbc   = (float*)(ws + OFF_DBC);
    ushort_t* dbc16 = (ushort_t*)(ws + OFF_DBC16);
    float*    delta = (float*)(ws + OFF_DELTA);
    ushort_t* yf    = (ushort_t*)(ws + OFF_YF);
    ushort_t* yb    = (ushort_t*)(ws + OFF_YB);
    ushort_t* yc16  = (ushort_t*)(ws + OFF_YC16);
    ushort_t* x16   = (ushort_t*)(ws + OFF_X16);
    ushort_t* win16 = (ushort_t*)(ws + OFF_WIN16);
    ushort_t* wx16  = (ushort_t*)(ws + OFF_WX16);
    ushort_t* wdt16 = (ushort_t*)(ws + OFF_WDT16);
    ushort_t* wout16= (ushort_t*)(ws + OFF_WOUT16);
    float*    part  = (float*)(ws + OFF_PART);

    dim3 blk(256);

    // fused fp32->bf16 casts (7 tensors, 1 launch)
    CastArgs ca;
    const int n4s[7] = {524288, 1048576, 49152, 49152, 32768, 32768, 524288};
    ca.seg[0] = { (const float4*)x,     (ushort4*)x16 };
    ca.seg[1] = { (const float4*)W_in,  (ushort4*)win16 };
    ca.seg[2] = { (const float4*)Wx,    (ushort4*)wx16 };
    ca.seg[3] = { (const float4*)Wx_b,  (ushort4*)(wx16 + 96 * 2048) };
    ca.seg[4] = { (const float4*)Wdt,   (ushort4*)wdt16 };
    ca.seg[5] = { (const float4*)Wdt_b, (ushort4*)(wdt16 + 2048 * 64) };
    ca.seg[6] = { (const float4*)W_out, (ushort4*)wout16 };
    ca.start[0] = 0;
    for (int i = 0; i < 7; i++) ca.start[i + 1] = ca.start[i] + n4s[i];
    cast_multi<<<(ca.start[7] + 255) / 256, blk, 0, stream>>>(ca);

    // G1: xz = x @ W_in^T  (2048 x 4096, K=1024)
    gemm_bt<0><<<dim3(32, 16), blk, 0, stream>>>(x16, 1024, win16, 1024, xz, 4096, 1024);

    // conv + silu, both branches -> bf16 x
    conv_silu_kernel<<<32768, blk, 0, stream>>>(xz, conv_w, conv_b, conv_w_b, conv_b_b, xc16);

    // G2: dbc partials (split-K=4, both branches) + reduce
    gemm_g2<<<dim3(4, 16, 2), blk, 0, stream>>>(xc16, wx16, part);
    reduce_dbc<<<384, blk, 0, stream>>>((const float4*)part, (float4*)dbc, (ushort4*)dbc16);

    // G3: delta = softplus(dbc[:, :64] @ Wdt^T + b_dt), both branches
    gemm_g3<<<dim3(16, 16, 2), blk, 0, stream>>>(dbc16, wdt16, delta, b_dt, b_dt_b);

    // selective scan + gating, both branches
    scan_kernel<<<256, blk, 0, stream>>>(delta, xc16, dbc, xz, A_log, A_log_b, Dp, Dp_b, yf, yb);

    // combine fwd + reversed bwd
    combine_kernel<<<4096, blk, 0, stream>>>((const uint2*)yf, (const uint2*)yb, (uint2*)yc16);

    // G4: out = y_comb @ W_out^T  (2048 x 1024, K=2048)
    gemm_bt<0><<<dim3(8, 16), blk, 0, stream>>>(yc16, 2048, wout16, 2048, out, 1024, 2048);
}

// Round 4
// 351.181 us; speedup vs baseline: 2.2996x; 1.1500x over previous
//
#include <hip/hip_runtime.h>
#include <hip/hip_bf16.h>
#include <stdint.h>

typedef unsigned short ushort_t;
typedef __attribute__((ext_vector_type(8))) short short8;
typedef __attribute__((ext_vector_type(4))) float f32x4;

__device__ __forceinline__ float b2f(ushort_t u) {
    union { uint32_t i; float f; } v; v.i = ((uint32_t)u) << 16; return v.f;
}
__device__ __forceinline__ ushort_t f2b(float f) {
    union { float f; uint32_t i; } v; v.f = f;
    uint32_t r = v.i + 0x7fff + ((v.i >> 16) & 1);
    return (ushort_t)(r >> 16);
}

// ---------------------------------------------------------------------------
// Fused multi-tensor fp32 -> bf16 cast (7 segments, 1 launch)
// ---------------------------------------------------------------------------
struct CastSeg { const float4* src; ushort4* dst; };
struct CastArgs { CastSeg seg[7]; int start[8]; };

__global__ __launch_bounds__(256) void cast_multi(CastArgs a)
{
    int g = blockIdx.x * 256 + threadIdx.x;
    if (g >= a.start[7]) return;
    int s = 0;
#pragma unroll
    for (int i = 1; i < 7; i++) s += (g >= a.start[i]);
    int i = g - a.start[s];
    float4 v = a.seg[s].src[i];
    ushort4 o;
    o.x = f2b(v.x); o.y = f2b(v.y); o.z = f2b(v.z); o.w = f2b(v.w);
    a.seg[s].dst[i] = o;
}

// ---------------------------------------------------------------------------
// bf16 GEMM: C[m,n] = sum_k A[m,k]*B[n,k]. BM=BN=128, BK=32, 4 waves 2x2.
// ---------------------------------------------------------------------------
#define BM 128
#define BN 128
#define BK 32

template <int EPI>
__global__ __launch_bounds__(256) void gemm_bt(
    const ushort_t* __restrict__ A, int lda,
    const ushort_t* __restrict__ B, int ldb,
    float* __restrict__ Cout, int ldc, int Kd)
{
    __shared__ ushort_t As[BM * BK];
    __shared__ ushort_t Bs[BN * BK];

    const int tid  = threadIdx.x;
    const int m0   = blockIdx.y * BM;
    const int n0   = blockIdx.x * BN;
    const int wave = tid >> 6;
    const int lane = tid & 63;
    const int wm   = (wave >> 1) * 64;
    const int wn   = (wave & 1) * 64;
    const int lr   = lane & 15;
    const int quad = lane >> 4;

    f32x4 acc[4][4];
#pragma unroll
    for (int i = 0; i < 4; i++)
#pragma unroll
        for (int j = 0; j < 4; j++) acc[i][j] = f32x4{0.f, 0.f, 0.f, 0.f};

    const int srow  = tid >> 1;
    const int scol8 = (tid & 1) * 2;

    for (int k0 = 0; k0 < Kd; k0 += BK) {
#pragma unroll
        for (int q = 0; q < 2; q++) {
            int c8 = scol8 + q;
            *(uint4*)(&As[srow * BK + c8 * 8]) =
                *(const uint4*)(A + (size_t)(m0 + srow) * lda + k0 + c8 * 8);
        }
#pragma unroll
        for (int q = 0; q < 2; q++) {
            int c8 = scol8 + q;
            *(uint4*)(&Bs[srow * BK + c8 * 8]) =
                *(const uint4*)(B + (size_t)(n0 + srow) * ldb + k0 + c8 * 8);
        }
        __syncthreads();

        short8 af[4], bf[4];
#pragma unroll
        for (int i = 0; i < 4; i++)
            af[i] = *(const short8*)(&As[(wm + i * 16 + lr) * BK + quad * 8]);
#pragma unroll
        for (int j = 0; j < 4; j++)
            bf[j] = *(const short8*)(&Bs[(wn + j * 16 + lr) * BK + quad * 8]);
#pragma unroll
        for (int i = 0; i < 4; i++)
#pragma unroll
            for (int j = 0; j < 4; j++)
                acc[i][j] = __builtin_amdgcn_mfma_f32_16x16x32_bf16(af[i], bf[j], acc[i][j], 0, 0, 0);
        __syncthreads();
    }

#pragma unroll
    for (int i = 0; i < 4; i++) {
        int m = m0 + wm + i * 16 + quad * 4;
#pragma unroll
        for (int j = 0; j < 4; j++) {
            int n = n0 + wn + j * 16 + lr;
#pragma unroll
            for (int r = 0; r < 4; r++)
                Cout[(size_t)(m + r) * ldc + n] = acc[i][j][r];
        }
    }
}

// ---------------------------------------------------------------------------
// G2: dbc partials. grid (SK=4, M/128=16, br=2). N=96 guarded.
// ---------------------------------------------------------------------------
__global__ __launch_bounds__(256) void gemm_g2(
    const ushort_t* __restrict__ xc, const ushort_t* __restrict__ wx,
    float* __restrict__ part)
{
    __shared__ ushort_t As[BM * BK];
    __shared__ ushort_t Bs[BN * BK];

    const int sk = blockIdx.x, mb = blockIdx.y, br = blockIdx.z;
    const ushort_t* A = xc + (size_t)br * 2048 * 2048;
    const ushort_t* B = wx + (size_t)br * 96 * 2048;
    float* C = part + (size_t)(sk * 2 + br) * 2048 * 96;
    const int m0 = mb * BM;
    const int kb = sk * 512;

    const int tid  = threadIdx.x;
    const int wave = tid >> 6;
    const int lane = tid & 63;
    const int wm   = (wave >> 1) * 64;
    const int wn   = (wave & 1) * 64;
    const int lr   = lane & 15;
    const int quad = lane >> 4;

    f32x4 acc[4][4];
#pragma unroll
    for (int i = 0; i < 4; i++)
#pragma unroll
        for (int j = 0; j < 4; j++) acc[i][j] = f32x4{0.f, 0.f, 0.f, 0.f};

    const int srow  = tid >> 1;
    const int scol8 = (tid & 1) * 2;

    for (int k0 = kb; k0 < kb + 512; k0 += BK) {
#pragma unroll
        for (int q = 0; q < 2; q++) {
            int c8 = scol8 + q;
            *(uint4*)(&As[srow * BK + c8 * 8]) =
                *(const uint4*)(A + (size_t)(m0 + srow) * 2048 + k0 + c8 * 8);
        }
#pragma unroll
        for (int q = 0; q < 2; q++) {
            int c8 = scol8 + q;
            uint4 vb = make_uint4(0u, 0u, 0u, 0u);
            if (srow < 96) vb = *(const uint4*)(B + (size_t)srow * 2048 + k0 + c8 * 8);
            *(uint4*)(&Bs[srow * BK + c8 * 8]) = vb;
        }
        __syncthreads();

        short8 af[4], bf[4];
#pragma unroll
        for (int i = 0; i < 4; i++)
            af[i] = *(const short8*)(&As[(wm + i * 16 + lr) * BK + quad * 8]);
#pragma unroll
        for (int j = 0; j < 4; j++)
            bf[j] = *(const short8*)(&Bs[(wn + j * 16 + lr) * BK + quad * 8]);
#pragma unroll
        for (int i = 0; i < 4; i++)
#pragma unroll
            for (int j = 0; j < 4; j++)
                acc[i][j] = __builtin_amdgcn_mfma_f32_16x16x32_bf16(af[i], bf[j], acc[i][j], 0, 0, 0);
        __syncthreads();
    }

#pragma unroll
    for (int i = 0; i < 4; i++) {
        int m = m0 + wm + i * 16 + quad * 4;
#pragma unroll
        for (int j = 0; j < 4; j++) {
            int n = wn + j * 16 + lr;
            if (n < 96) {
#pragma unroll
                for (int r = 0; r < 4; r++)
                    C[(size_t)(m + r) * 96 + n] = acc[i][j][r];
            }
        }
    }
}

__global__ __launch_bounds__(256) void reduce_dbc(
    const float4* __restrict__ part, float4* __restrict__ dbc,
    ushort4* __restrict__ dbc16)
{
    int g = blockIdx.x * 256 + threadIdx.x;   // 98304 total
    const int S = 2 * 2048 * 96 / 4;
    float4 a = part[g], b = part[g + S], c = part[g + 2 * S], d = part[g + 3 * S];
    float4 r; r.x = a.x + b.x + c.x + d.x; r.y = a.y + b.y + c.y + d.y;
    r.z = a.z + b.z + c.z + d.z; r.w = a.w + b.w + c.w + d.w;
    dbc[g] = r;
    ushort4 o; o.x = f2b(r.x); o.y = f2b(r.y); o.z = f2b(r.z); o.w = f2b(r.w);
    dbc16[g] = o;
}

// ---------------------------------------------------------------------------
// G3: delta = softplus(dbc[:, :64] @ Wdt^T + b_dt), both branches via grid z.
// ---------------------------------------------------------------------------
__global__ __launch_bounds__(256) void gemm_g3(
    const ushort_t* __restrict__ dbc16, const ushort_t* __restrict__ wdt,
    float* __restrict__ delta,
    const float* __restrict__ bdt_f, const float* __restrict__ bdt_b)
{
    __shared__ ushort_t As[BM * BK];
    __shared__ ushort_t Bs[BN * BK];

    const int br = blockIdx.z;
    const ushort_t* A = dbc16 + (size_t)br * 2048 * 96;
    const ushort_t* B = wdt + (size_t)br * 2048 * 64;
    float* C = delta + (size_t)br * 2048 * 2048;
    const float* bias = br ? bdt_b : bdt_f;

    const int tid  = threadIdx.x;
    const int m0   = blockIdx.y * BM;
    const int n0   = blockIdx.x * BN;
    const int wave = tid >> 6;
    const int lane = tid & 63;
    const int wm   = (wave >> 1) * 64;
    const int wn   = (wave & 1) * 64;
    const int lr   = lane & 15;
    const int quad = lane >> 4;

    f32x4 acc[4][4];
#pragma unroll
    for (int i = 0; i < 4; i++)
#pragma unroll
        for (int j = 0; j < 4; j++) acc[i][j] = f32x4{0.f, 0.f, 0.f, 0.f};

    const int srow  = tid >> 1;
    const int scol8 = (tid & 1) * 2;

    for (int k0 = 0; k0 < 64; k0 += BK) {
#pragma unroll
        for (int q = 0; q < 2; q++) {
            int c8 = scol8 + q;
            *(uint4*)(&As[srow * BK + c8 * 8]) =
                *(const uint4*)(A + (size_t)(m0 + srow) * 96 + k0 + c8 * 8);
        }
#pragma unroll
        for (int q = 0; q < 2; q++) {
            int c8 = scol8 + q;
            *(uint4*)(&Bs[srow * BK + c8 * 8]) =
                *(const uint4*)(B + (size_t)(n0 + srow) * 64 + k0 + c8 * 8);
        }
        __syncthreads();

        short8 af[4], bf[4];
#pragma unroll
        for (int i = 0; i < 4; i++)
            af[i] = *(const short8*)(&As[(wm + i * 16 + lr) * BK + quad * 8]);
#pragma unroll
        for (int j = 0; j < 4; j++)
            bf[j] = *(const short8*)(&Bs[(wn + j * 16 + lr) * BK + quad * 8]);
#pragma unroll
        for (int i = 0; i < 4; i++)
#pragma unroll
            for (int j = 0; j < 4; j++)
                acc[i][j] = __builtin_amdgcn_mfma_f32_16x16x32_bf16(af[i], bf[j], acc[i][j], 0, 0, 0);
        __syncthreads();
    }

#pragma unroll
    for (int i = 0; i < 4; i++) {
        int m = m0 + wm + i * 16 + quad * 4;
#pragma unroll
        for (int j = 0; j < 4; j++) {
            int n = n0 + wn + j * 16 + lr;
            float bn = bias[n];
#pragma unroll
            for (int r = 0; r < 4; r++) {
                float x = acc[i][j][r] + bn;
                C[(size_t)(m + r) * 2048 + n] = (x > 20.f) ? x : log1pf(expf(x));
            }
        }
    }
}

// ---------------------------------------------------------------------------
// Causal depthwise conv (K=4) + bias + silu, both branches, bf16 out.
// ---------------------------------------------------------------------------
__global__ __launch_bounds__(256) void conv_silu_kernel(
    const float* __restrict__ xz,
    const float* __restrict__ w_f, const float* __restrict__ cb_f,
    const float* __restrict__ w_b, const float* __restrict__ cb_b,
    ushort_t* __restrict__ xc16)
{
    int g = blockIdx.x * 256 + threadIdx.x;
    int e  = g & 2047;
    int t  = (g >> 11) & 511;
    int b  = (g >> 20) & 3;
    int br = g >> 22;

    const float* w  = br ? w_b  : w_f;
    const float* cb = br ? cb_b : cb_f;

    float acc = cb[e];
    float4 wv = *(const float4*)(w + e * 4);
    float wk[4] = { wv.x, wv.y, wv.z, wv.w };

#pragma unroll
    for (int k = 0; k < 4; k++) {
        int tp = t - 3 + k;
        if (tp >= 0) {
            int row = br ? (511 - tp) : tp;
            acc += wk[k] * xz[((size_t)(b * 512 + row)) * 4096 + e];
        }
    }
    float s = acc / (1.f + __expf(-acc));
    xc16[g] = f2b(s);
}

// ---------------------------------------------------------------------------
// Selective scan v3: 512 blocks (2/CU), block = (br, b, 32 e). Thread owns
// 2 states (n2, n2+8). Time-fast (transposed) LDS layouts, 4-t batched inner
// loop, padded rows, register-kept x for the flush. 2 waves/SIMD.
// ---------------------------------------------------------------------------
__global__ __launch_bounds__(256) void scan_kernel(
    const float* __restrict__ delta,      // [2][B][L][ED] fp32
    const ushort_t* __restrict__ xc,      // [2][B][L][ED] bf16
    const float* __restrict__ dbc,        // [2][B][L][96] fp32
    const float* __restrict__ xz,         // [B][L][4096] fp32 (z half)
    const float* __restrict__ Alog_f, const float* __restrict__ Alog_b,
    const float* __restrict__ Dp_f,   const float* __restrict__ Dp_b,
    ushort_t* __restrict__ yf, ushort_t* __restrict__ yb)
{
    const int blk = blockIdx.x;            // 0..511
    const int eg = blk & 63;               // 64 e-groups of 32
    const int b  = (blk >> 6) & 3;
    const int br = blk >> 8;
    const int e0 = eg * 32;

    const int tid = threadIdx.x;
    const int n2  = tid & 7;               // states n2, n2+8
    const int el  = tid >> 3;              // 0..31 (e-local)
    const int e   = e0 + el;

    const float* Alog = br ? Alog_b : Alog_f;
    const float* Dpp  = br ? Dp_b   : Dp_f;
    const float A0 = -__expf(Alog[e * 16 + n2]);
    const float A1 = -__expf(Alog[e * 16 + n2 + 8]);

    size_t tb = ((size_t)br * 4 + b) * 512;
    const float*    dlt  = delta + tb * 2048;
    const ushort_t* xcb  = xc    + tb * 2048;
    const float*    dbcb = dbc   + tb * 96;
    ushort_t* y = (br ? yb : yf) + (size_t)b * 512 * 2048;

    // time-fast LDS (row-padded against bank conflicts)
    __shared__ float    sd[2][32][68];     // d[e][t]
    __shared__ ushort_t sx[2][32][72];     // x[e][t]
    __shared__ float    sB[2][16][68];     // B[n][t]
    __shared__ float    sC[2][16][68];     // C[n][t]
    __shared__ float    sy[64][33];        // y[t][e]

    // staging / flush mapping: row = t-local, seg = 8-elem column group
    const int stt = tid >> 2;              // 0..63
    const int seg = tid & 3;               // 0..3

    float4 rD0 = *(const float4*)(Dpp + e0 + seg * 8);
    float4 rD1 = *(const float4*)(Dpp + e0 + seg * 8 + 4);

    float4 rd0, rd1, rb0, rb1; uint4 rx, rx_keep;

    auto load_regs = [&](int c) {
        int t0 = c * 64;
        const float* dsrc = dlt + (size_t)(t0 + stt) * 2048 + e0 + seg * 8;
        rd0 = *(const float4*)(dsrc);
        rd1 = *(const float4*)(dsrc + 4);
        rx  = *(const uint4*)(xcb + (size_t)(t0 + stt) * 2048 + e0 + seg * 8);
        const float* bsrc = dbcb + (size_t)(t0 + stt) * 96 + 64 + seg * 8;
        rb0 = *(const float4*)(bsrc);
        rb1 = *(const float4*)(bsrc + 4);
    };
    auto write_lds = [&](int buf) {
        // d transposed: sd[e][t]
        sd[buf][seg * 8 + 0][stt] = rd0.x;
        sd[buf][seg * 8 + 1][stt] = rd0.y;
        sd[buf][seg * 8 + 2][stt] = rd0.z;
        sd[buf][seg * 8 + 3][stt] = rd0.w;
        sd[buf][seg * 8 + 4][stt] = rd1.x;
        sd[buf][seg * 8 + 5][stt] = rd1.y;
        sd[buf][seg * 8 + 6][stt] = rd1.z;
        sd[buf][seg * 8 + 7][stt] = rd1.w;
        // x transposed: sx[e][t]
        const uint32_t xw[4] = { rx.x, rx.y, rx.z, rx.w };
#pragma unroll
        for (int k = 0; k < 4; k++) {
            sx[buf][seg * 8 + 2 * k][stt]     = (ushort_t)(xw[k] & 0xffff);
            sx[buf][seg * 8 + 2 * k + 1][stt] = (ushort_t)(xw[k] >> 16);
        }
        // B/C transposed: seg 0,1 -> B rows, seg 2,3 -> C rows
        float* dst0 = (seg < 2) ? &sB[buf][seg * 8][0] : &sC[buf][(seg - 2) * 8][0];
        dst0[0 * 68 + stt] = rb0.x;
        dst0[1 * 68 + stt] = rb0.y;
        dst0[2 * 68 + stt] = rb0.z;
        dst0[3 * 68 + stt] = rb0.w;
        dst0[4 * 68 + stt] = rb1.x;
        dst0[5 * 68 + stt] = rb1.y;
        dst0[6 * 68 + stt] = rb1.z;
        dst0[7 * 68 + stt] = rb1.w;
    };

    float h0 = 0.f, h1 = 0.f;

    load_regs(0);
    write_lds(0);
    rx_keep = rx;

    for (int c = 0; c < 8; ++c) {
        if (c < 7) load_regs(c + 1);
        __syncthreads();                    // staging for chunk c visible
        const int buf = c & 1;

#pragma unroll 4
        for (int tq = 0; tq < 64; tq += 4) {
            float4 dv = *(const float4*)(&sd[buf][el][tq]);
            uint2  xv = *(const uint2*)(&sx[buf][el][tq]);
            float4 B0 = *(const float4*)(&sB[buf][n2][tq]);
            float4 B1 = *(const float4*)(&sB[buf][n2 + 8][tq]);
            float4 C0 = *(const float4*)(&sC[buf][n2][tq]);
            float4 C1 = *(const float4*)(&sC[buf][n2 + 8][tq]);

            float x0 = b2f((ushort_t)(xv.x & 0xffff));
            float x1 = b2f((ushort_t)(xv.x >> 16));
            float x2 = b2f((ushort_t)(xv.y & 0xffff));
            float x3 = b2f((ushort_t)(xv.y >> 16));

            float e00 = __expf(dv.x * A0), e01 = __expf(dv.y * A0);
            float e02 = __expf(dv.z * A0), e03 = __expf(dv.w * A0);
            float e10 = __expf(dv.x * A1), e11 = __expf(dv.y * A1);
            float e12 = __expf(dv.z * A1), e13 = __expf(dv.w * A1);

            float dx0 = dv.x * x0, dx1 = dv.y * x1;
            float dx2 = dv.z * x2, dx3 = dv.w * x3;

            h0 = e00 * h0 + dx0 * B0.x;  h1 = e10 * h1 + dx0 * B1.x;
            float p0 = h0 * C0.x + h1 * C1.x;
            h0 = e01 * h0 + dx1 * B0.y;  h1 = e11 * h1 + dx1 * B1.y;
            float p1 = h0 * C0.y + h1 * C1.y;
            h0 = e02 * h0 + dx2 * B0.z;  h1 = e12 * h1 + dx2 * B1.z;
            float p2 = h0 * C0.z + h1 * C1.z;
            h0 = e03 * h0 + dx3 * B0.w;  h1 = e13 * h1 + dx3 * B1.w;
            float p3 = h0 * C0.w + h1 * C1.w;

            p0 += __shfl_xor(p0, 1); p0 += __shfl_xor(p0, 2); p0 += __shfl_xor(p0, 4);
            p1 += __shfl_xor(p1, 1); p1 += __shfl_xor(p1, 2); p1 += __shfl_xor(p1, 4);
            p2 += __shfl_xor(p2, 1); p2 += __shfl_xor(p2, 2); p2 += __shfl_xor(p2, 4);
            p3 += __shfl_xor(p3, 1); p3 += __shfl_xor(p3, 2); p3 += __shfl_xor(p3, 4);

            if (n2 == 0) {
                sy[tq + 0][el] = p0;
                sy[tq + 1][el] = p1;
                sy[tq + 2][el] = p2;
                sy[tq + 3][el] = p3;
            }
        }
        __syncthreads();                    // sy complete

        // flush chunk c: gate with z*silu + D*x, store bf16
        {
            int row  = c * 64 + stt;
            int orow = br ? (511 - row) : row;
            const float* zsrc = xz + ((size_t)(b * 512 + orow)) * 4096 + 2048 + e0 + seg * 8;
            float4 z0 = *(const float4*)(zsrc);
            float4 z1 = *(const float4*)(zsrc + 4);
            float pv[8];
#pragma unroll
            for (int k = 0; k < 8; k++) pv[k] = sy[stt][seg * 8 + k];
            const uint32_t xw[4] = { rx_keep.x, rx_keep.y, rx_keep.z, rx_keep.w };
            float xvv[8];
#pragma unroll
            for (int k = 0; k < 4; k++) {
                xvv[2 * k]     = b2f((ushort_t)(xw[k] & 0xffff));
                xvv[2 * k + 1] = b2f((ushort_t)(xw[k] >> 16));
            }
            const float Dv[8] = { rD0.x, rD0.y, rD0.z, rD0.w, rD1.x, rD1.y, rD1.z, rD1.w };
            const float zv[8] = { z0.x, z0.y, z0.z, z0.w, z1.x, z1.y, z1.z, z1.w };
            uint32_t op[4];
#pragma unroll
            for (int k = 0; k < 4; k++) {
                float ga = (pv[2 * k]     + Dv[2 * k]     * xvv[2 * k])     *
                           (zv[2 * k]     / (1.f + __expf(-zv[2 * k])));
                float gb = (pv[2 * k + 1] + Dv[2 * k + 1] * xvv[2 * k + 1]) *
                           (zv[2 * k + 1] / (1.f + __expf(-zv[2 * k + 1])));
                op[k] = (uint32_t)f2b(ga) | ((uint32_t)f2b(gb) << 16);
            }
            *(uint4*)(y + (size_t)row * 2048 + e0 + seg * 8) =
                make_uint4(op[0], op[1], op[2], op[3]);
        }

        if (c < 7) {
            write_lds((c + 1) & 1);
            rx_keep = rx;
        }
    }
}

__global__ __launch_bounds__(256) void combine_kernel(
    const uint2* __restrict__ yf, const uint2* __restrict__ yb,
    uint2* __restrict__ yc)
{
    int g = blockIdx.x * 256 + threadIdx.x;   // 1048576 total
    int e4 = g & 511;
    int t  = (g >> 9) & 511;
    int b  = g >> 18;
    uint2 a = yf[g];
    uint2 c = yb[((size_t)(b * 512 + 511 - t)) * 512 + e4];
    uint2 o;
    o.x = (uint32_t)f2b(0.5f * (b2f(a.x & 0xffff) + b2f(c.x & 0xffff))) |
          ((uint32_t)f2b(0.5f * (b2f(a.x >> 16) + b2f(c.x >> 16))) << 16);
    o.y = (uint32_t)f2b(0.5f * (b2f(a.y & 0xffff) + b2f(c.y & 0xffff))) |
          ((uint32_t)f2b(0.5f * (b2f(a.y >> 16) + b2f(c.y >> 16))) << 16);
    yc[g] = o;
}

// ---------------------------------------------------------------------------
// Workspace layout (bytes)
// ---------------------------------------------------------------------------
static const size_t TT = 2048;  // B_SZ * L
static const size_t OFF_XZ    = 0;                          // 32MB
static const size_t OFF_XC16  = OFF_XZ    + TT*4096*4;      // 16MB
static const size_t OFF_DBC   = OFF_XC16  + 2*TT*2048*2;    // 1.5MB
static const size_t OFF_DBC16 = OFF_DBC   + 2*TT*96*4;      // .75MB
static const size_t OFF_DELTA = OFF_DBC16 + 2*TT*96*2;      // 32MB
static const size_t OFF_YF    = OFF_DELTA + 2*TT*2048*4;    // 8MB
static const size_t OFF_YB    = OFF_YF    + TT*2048*2;      // 8MB
static const size_t OFF_YC16  = OFF_YB    + TT*2048*2;      // 8MB
static const size_t OFF_X16   = OFF_YC16  + TT*2048*2;      // 4MB
static const size_t OFF_WIN16 = OFF_X16   + TT*1024*2;      // 8MB
static const size_t OFF_WX16  = OFF_WIN16 + 4096*1024*2;    // .75MB
static const size_t OFF_WDT16 = OFF_WX16  + 2*96*2048*2;    // .5MB
static const size_t OFF_WOUT16= OFF_WDT16 + 2*2048*64*2;    // 4MB
static const size_t OFF_PART  = OFF_WOUT16+ 1024*2048*2;    // 6MB

extern "C" void kernel_launch(void* const* d_in, const int* in_sizes, int n_in,
                              void* d_out, int out_size, void* d_ws, size_t ws_size,
                              hipStream_t stream) {
    const float* x       = (const float*)d_in[0];
    const float* W_in    = (const float*)d_in[1];
    const float* conv_w  = (const float*)d_in[2];
    const float* conv_b  = (const float*)d_in[3];
    const float* Wx      = (const float*)d_in[4];
    const float* Wdt     = (const float*)d_in[5];
    const float* b_dt    = (const float*)d_in[6];
    const float* A_log   = (const float*)d_in[7];
    const float* Dp      = (const float*)d_in[8];
    const float* conv_w_b= (const float*)d_in[9];
    const float* conv_b_b= (const float*)d_in[10];
    const float* Wx_b    = (const float*)d_in[11];
    const float* Wdt_b   = (const float*)d_in[12];
    const float* b_dt_b  = (const float*)d_in[13];
    const float* A_log_b = (const float*)d_in[14];
    const float* Dp_b    = (const float*)d_in[15];
    const float* W_out   = (const float*)d_in[16];
    float* out = (float*)d_out;

    char* ws = (char*)d_ws;
    float*    xz    = (float*)(ws + OFF_XZ);
    ushort_t* xc16  = (ushort_t*)(ws + OFF_XC16);
    float*    dbc   = (float*)(ws + OFF_DBC);
    ushort_t* dbc16 = (ushort_t*)(ws + OFF_DBC16);
    float*    delta = (float*)(ws + OFF_DELTA);
    ushort_t* yf    = (ushort_t*)(ws + OFF_YF);
    ushort_t* yb    = (ushort_t*)(ws + OFF_YB);
    ushort_t* yc16  = (ushort_t*)(ws + OFF_YC16);
    ushort_t* x16   = (ushort_t*)(ws + OFF_X16);
    ushort_t* win16 = (ushort_t*)(ws + OFF_WIN16);
    ushort_t* wx16  = (ushort_t*)(ws + OFF_WX16);
    ushort_t* wdt16 = (ushort_t*)(ws + OFF_WDT16);
    ushort_t* wout16= (ushort_t*)(ws + OFF_WOUT16);
    float*    part  = (float*)(ws + OFF_PART);

    dim3 blk(256);

    // fused fp32->bf16 casts (7 tensors, 1 launch)
    CastArgs ca;
    const int n4s[7] = {524288, 1048576, 49152, 49152, 32768, 32768, 524288};
    ca.seg[0] = { (const float4*)x,     (ushort4*)x16 };
    ca.seg[1] = { (const float4*)W_in,  (ushort4*)win16 };
    ca.seg[2] = { (const float4*)Wx,    (ushort4*)wx16 };
    ca.seg[3] = { (const float4*)Wx_b,  (ushort4*)(wx16 + 96 * 2048) };
    ca.seg[4] = { (const float4*)Wdt,   (ushort4*)wdt16 };
    ca.seg[5] = { (const float4*)Wdt_b, (ushort4*)(wdt16 + 2048 * 64) };
    ca.seg[6] = { (const float4*)W_out, (ushort4*)wout16 };
    ca.start[0] = 0;
    for (int i = 0; i < 7; i++) ca.start[i + 1] = ca.start[i] + n4s[i];
    cast_multi<<<(ca.start[7] + 255) / 256, blk, 0, stream>>>(ca);

    // G1: xz = x @ W_in^T  (2048 x 4096, K=1024)
    gemm_bt<0><<<dim3(32, 16), blk, 0, stream>>>(x16, 1024, win16, 1024, xz, 4096, 1024);

    // conv + silu, both branches -> bf16 x
    conv_silu_kernel<<<32768, blk, 0, stream>>>(xz, conv_w, conv_b, conv_w_b, conv_b_b, xc16);

    // G2: dbc partials (split-K=4, both branches) + reduce
    gemm_g2<<<dim3(4, 16, 2), blk, 0, stream>>>(xc16, wx16, part);
    reduce_dbc<<<384, blk, 0, stream>>>((const float4*)part, (float4*)dbc, (ushort4*)dbc16);

    // G3: delta = softplus(dbc[:, :64] @ Wdt^T + b_dt), both branches
    gemm_g3<<<dim3(16, 16, 2), blk, 0, stream>>>(dbc16, wdt16, delta, b_dt, b_dt_b);

    // selective scan + gating, both branches (v3: 512 blocks, 2 waves/SIMD)
    scan_kernel<<<512, blk, 0, stream>>>(delta, xc16, dbc, xz, A_log, A_log_b, Dp, Dp_b, yf, yb);

    // combine fwd + reversed bwd
    combine_kernel<<<4096, blk, 0, stream>>>((const uint2*)yf, (const uint2*)yb, (uint2*)yc16);

    // G4: out = y_comb @ W_out^T  (2048 x 1024, K=2048)
    gemm_bt<0><<<dim3(8, 16), blk, 0, stream>>>(yc16, 2048, wout16, 2048, out, 1024, 2048);
}

// Round 5
// 329.810 us; speedup vs baseline: 2.4486x; 1.0648x over previous
//
#include <hip/hip_runtime.h>
#include <hip/hip_bf16.h>
#include <stdint.h>

typedef unsigned short ushort_t;
typedef __attribute__((ext_vector_type(8))) short short8;
typedef __attribute__((ext_vector_type(4))) float f32x4;

__device__ __forceinline__ float b2f(ushort_t u) {
    union { uint32_t i; float f; } v; v.i = ((uint32_t)u) << 16; return v.f;
}
__device__ __forceinline__ ushort_t f2b(float f) {
    union { float f; uint32_t i; } v; v.f = f;
    uint32_t r = v.i + 0x7fff + ((v.i >> 16) & 1);
    return (ushort_t)(r >> 16);
}

// async global->LDS, 16B per lane; lds base must be wave-uniform
__device__ __forceinline__ void ll16(const ushort_t* g, ushort_t* l) {
    __builtin_amdgcn_global_load_lds(
        (const __attribute__((address_space(1))) uint32_t*)g,
        (__attribute__((address_space(3))) uint32_t*)l, 16, 0, 0);
}

// DPP cross-lane add (VALU pipe, replaces ds_bpermute shuffles)
template <int CTRL>
__device__ __forceinline__ float dpp_add(float p) {
    int v = __builtin_amdgcn_update_dpp(0, __float_as_int(p), CTRL, 0xF, 0xF, true);
    return p + __int_as_float(v);
}
#define DPP_XOR1 0xB1   // quad_perm(1,0,3,2)
#define DPP_XOR2 0x4E   // quad_perm(2,3,0,1)
#define DPP_HMIR 0x141  // row_half_mirror (xor7 within 8)

// ---------------------------------------------------------------------------
// Fused multi-tensor fp32 -> bf16 cast (7 segments, 1 launch)
// ---------------------------------------------------------------------------
struct CastSeg { const float4* src; ushort4* dst; };
struct CastArgs { CastSeg seg[7]; int start[8]; };

__global__ __launch_bounds__(256) void cast_multi(CastArgs a)
{
    int g = blockIdx.x * 256 + threadIdx.x;
    if (g >= a.start[7]) return;
    int s = 0;
#pragma unroll
    for (int i = 1; i < 7; i++) s += (g >= a.start[i]);
    int i = g - a.start[s];
    float4 v = a.seg[s].src[i];
    ushort4 o;
    o.x = f2b(v.x); o.y = f2b(v.y); o.z = f2b(v.z); o.w = f2b(v.w);
    a.seg[s].dst[i] = o;
}

// ---------------------------------------------------------------------------
// bf16 GEMM 128x128, BK=32, async LDS staging. C[m,n] = sum_k A[m,k]*B[n,k].
// ---------------------------------------------------------------------------
#define BK 32

__global__ __launch_bounds__(256) void gemm_bt(
    const ushort_t* __restrict__ A, int lda,
    const ushort_t* __restrict__ B, int ldb,
    float* __restrict__ Cout, int ldc, int Kd)
{
    __shared__ ushort_t As[128 * BK];
    __shared__ ushort_t Bs[128 * BK];

    const int tid  = threadIdx.x;
    const int m0   = blockIdx.y * 128;
    const int n0   = blockIdx.x * 128;
    const int wv   = tid >> 6;
    const int lane = tid & 63;
    const int wm   = (wv >> 1) * 64;
    const int wn   = (wv & 1) * 64;
    const int lr   = lane & 15;
    const int quad = lane >> 4;

    f32x4 acc[4][4];
#pragma unroll
    for (int i = 0; i < 4; i++)
#pragma unroll
        for (int j = 0; j < 4; j++) acc[i][j] = f32x4{0.f, 0.f, 0.f, 0.f};

    const int srA = wv * 32 + (lane >> 2);   // staging row base (q adds 16)
    const int scA = (lane & 3) * 8;          // staging col (elements)

    for (int k0 = 0; k0 < Kd; k0 += BK) {
        ll16(A + (size_t)(m0 + srA) * lda + k0 + scA,      &As[wv * 1024]);
        ll16(A + (size_t)(m0 + srA + 16) * lda + k0 + scA, &As[wv * 1024 + 512]);
        ll16(B + (size_t)(n0 + srA) * ldb + k0 + scA,      &Bs[wv * 1024]);
        ll16(B + (size_t)(n0 + srA + 16) * ldb + k0 + scA, &Bs[wv * 1024 + 512]);
        __syncthreads();

        short8 af[4], bf[4];
#pragma unroll
        for (int i = 0; i < 4; i++)
            af[i] = *(const short8*)(&As[(wm + i * 16 + lr) * BK + quad * 8]);
#pragma unroll
        for (int j = 0; j < 4; j++)
            bf[j] = *(const short8*)(&Bs[(wn + j * 16 + lr) * BK + quad * 8]);
#pragma unroll
        for (int i = 0; i < 4; i++)
#pragma unroll
            for (int j = 0; j < 4; j++)
                acc[i][j] = __builtin_amdgcn_mfma_f32_16x16x32_bf16(af[i], bf[j], acc[i][j], 0, 0, 0);
        __syncthreads();
    }

#pragma unroll
    for (int i = 0; i < 4; i++) {
        int m = m0 + wm + i * 16 + quad * 4;
#pragma unroll
        for (int j = 0; j < 4; j++) {
            int n = n0 + wn + j * 16 + lr;
#pragma unroll
            for (int r = 0; r < 4; r++)
                Cout[(size_t)(m + r) * ldc + n] = acc[i][j][r];
        }
    }
}

// ---------------------------------------------------------------------------
// bf16 GEMM 64x128 (BM=64) for G4: more blocks when N is small.
// ---------------------------------------------------------------------------
__global__ __launch_bounds__(256) void gemm_bt64(
    const ushort_t* __restrict__ A, int lda,
    const ushort_t* __restrict__ B, int ldb,
    float* __restrict__ Cout, int ldc, int Kd)
{
    __shared__ ushort_t As[64 * BK];
    __shared__ ushort_t Bs[128 * BK];

    const int tid  = threadIdx.x;
    const int m0   = blockIdx.y * 64;
    const int n0   = blockIdx.x * 128;
    const int wv   = tid >> 6;
    const int lane = tid & 63;
    const int wm   = (wv >> 1) * 32;
    const int wn   = (wv & 1) * 64;
    const int lr   = lane & 15;
    const int quad = lane >> 4;

    f32x4 acc[2][4];
#pragma unroll
    for (int i = 0; i < 2; i++)
#pragma unroll
        for (int j = 0; j < 4; j++) acc[i][j] = f32x4{0.f, 0.f, 0.f, 0.f};

    const int srA = wv * 16 + (lane >> 2);
    const int srB = wv * 32 + (lane >> 2);
    const int sc  = (lane & 3) * 8;

    for (int k0 = 0; k0 < Kd; k0 += BK) {
        ll16(A + (size_t)(m0 + srA) * lda + k0 + sc,      &As[wv * 512]);
        ll16(B + (size_t)(n0 + srB) * ldb + k0 + sc,      &Bs[wv * 1024]);
        ll16(B + (size_t)(n0 + srB + 16) * ldb + k0 + sc, &Bs[wv * 1024 + 512]);
        __syncthreads();

        short8 af[2], bf[4];
#pragma unroll
        for (int i = 0; i < 2; i++)
            af[i] = *(const short8*)(&As[(wm + i * 16 + lr) * BK + quad * 8]);
#pragma unroll
        for (int j = 0; j < 4; j++)
            bf[j] = *(const short8*)(&Bs[(wn + j * 16 + lr) * BK + quad * 8]);
#pragma unroll
        for (int i = 0; i < 2; i++)
#pragma unroll
            for (int j = 0; j < 4; j++)
                acc[i][j] = __builtin_amdgcn_mfma_f32_16x16x32_bf16(af[i], bf[j], acc[i][j], 0, 0, 0);
        __syncthreads();
    }

#pragma unroll
    for (int i = 0; i < 2; i++) {
        int m = m0 + wm + i * 16 + quad * 4;
#pragma unroll
        for (int j = 0; j < 4; j++) {
            int n = n0 + wn + j * 16 + lr;
#pragma unroll
            for (int r = 0; r < 4; r++)
                Cout[(size_t)(m + r) * ldc + n] = acc[i][j][r];
        }
    }
}

// ---------------------------------------------------------------------------
// G2: dbc partials. grid (SK=8, M/128=16, br=2). N=96: OOB B rows read
// adjacent workspace (garbage), their outputs are discarded at store.
// ---------------------------------------------------------------------------
__global__ __launch_bounds__(256) void gemm_g2(
    const ushort_t* __restrict__ xc, const ushort_t* __restrict__ wx,
    float* __restrict__ part)
{
    __shared__ ushort_t As[128 * BK];
    __shared__ ushort_t Bs[128 * BK];

    const int sk = blockIdx.x, mb = blockIdx.y, br = blockIdx.z;
    const ushort_t* A = xc + (size_t)br * 2048 * 2048;
    const ushort_t* B = wx + (size_t)br * 96 * 2048;
    float* C = part + (size_t)(sk * 2 + br) * 2048 * 96;
    const int m0 = mb * 128;
    const int kb = sk * 256;

    const int tid  = threadIdx.x;
    const int wv   = tid >> 6;
    const int lane = tid & 63;
    const int wm   = (wv >> 1) * 64;
    const int wn   = (wv & 1) * 64;
    const int lr   = lane & 15;
    const int quad = lane >> 4;

    f32x4 acc[4][4];
#pragma unroll
    for (int i = 0; i < 4; i++)
#pragma unroll
        for (int j = 0; j < 4; j++) acc[i][j] = f32x4{0.f, 0.f, 0.f, 0.f};

    const int srA = wv * 32 + (lane >> 2);
    const int sc  = (lane & 3) * 8;

    for (int k0 = kb; k0 < kb + 256; k0 += BK) {
        ll16(A + (size_t)(m0 + srA) * 2048 + k0 + sc,      &As[wv * 1024]);
        ll16(A + (size_t)(m0 + srA + 16) * 2048 + k0 + sc, &As[wv * 1024 + 512]);
        ll16(B + (size_t)(srA) * 2048 + k0 + sc,           &Bs[wv * 1024]);
        ll16(B + (size_t)(srA + 16) * 2048 + k0 + sc,      &Bs[wv * 1024 + 512]);
        __syncthreads();

        short8 af[4], bf[4];
#pragma unroll
        for (int i = 0; i < 4; i++)
            af[i] = *(const short8*)(&As[(wm + i * 16 + lr) * BK + quad * 8]);
#pragma unroll
        for (int j = 0; j < 4; j++)
            bf[j] = *(const short8*)(&Bs[(wn + j * 16 + lr) * BK + quad * 8]);
#pragma unroll
        for (int i = 0; i < 4; i++)
#pragma unroll
            for (int j = 0; j < 4; j++)
                acc[i][j] = __builtin_amdgcn_mfma_f32_16x16x32_bf16(af[i], bf[j], acc[i][j], 0, 0, 0);
        __syncthreads();
    }

#pragma unroll
    for (int i = 0; i < 4; i++) {
        int m = m0 + wm + i * 16 + quad * 4;
#pragma unroll
        for (int j = 0; j < 4; j++) {
            int n = wn + j * 16 + lr;
            if (n < 96) {
#pragma unroll
                for (int r = 0; r < 4; r++)
                    C[(size_t)(m + r) * 96 + n] = acc[i][j][r];
            }
        }
    }
}

__global__ __launch_bounds__(256) void reduce_dbc(
    const float4* __restrict__ part, ushort4* __restrict__ dbc16)
{
    int g = blockIdx.x * 256 + threadIdx.x;   // 98304 total
    const int S = 2 * 2048 * 96 / 4;
    float4 r = part[g];
#pragma unroll
    for (int i = 1; i < 8; i++) {
        float4 p = part[g + i * S];
        r.x += p.x; r.y += p.y; r.z += p.z; r.w += p.w;
    }
    ushort4 o; o.x = f2b(r.x); o.y = f2b(r.y); o.z = f2b(r.z); o.w = f2b(r.w);
    dbc16[g] = o;
}

// ---------------------------------------------------------------------------
// G3: delta = softplus(dbc[:, :64] @ Wdt^T + b_dt), both branches via grid z.
// ---------------------------------------------------------------------------
__global__ __launch_bounds__(256) void gemm_g3(
    const ushort_t* __restrict__ dbc16, const ushort_t* __restrict__ wdt,
    float* __restrict__ delta,
    const float* __restrict__ bdt_f, const float* __restrict__ bdt_b)
{
    __shared__ ushort_t As[128 * BK];
    __shared__ ushort_t Bs[128 * BK];

    const int br = blockIdx.z;
    const ushort_t* A = dbc16 + (size_t)br * 2048 * 96;
    const ushort_t* B = wdt + (size_t)br * 2048 * 64;
    float* C = delta + (size_t)br * 2048 * 2048;
    const float* bias = br ? bdt_b : bdt_f;

    const int tid  = threadIdx.x;
    const int m0   = blockIdx.y * 128;
    const int n0   = blockIdx.x * 128;
    const int wv   = tid >> 6;
    const int lane = tid & 63;
    const int wm   = (wv >> 1) * 64;
    const int wn   = (wv & 1) * 64;
    const int lr   = lane & 15;
    const int quad = lane >> 4;

    f32x4 acc[4][4];
#pragma unroll
    for (int i = 0; i < 4; i++)
#pragma unroll
        for (int j = 0; j < 4; j++) acc[i][j] = f32x4{0.f, 0.f, 0.f, 0.f};

    const int srA = wv * 32 + (lane >> 2);
    const int sc  = (lane & 3) * 8;

    for (int k0 = 0; k0 < 64; k0 += BK) {
        ll16(A + (size_t)(m0 + srA) * 96 + k0 + sc,       &As[wv * 1024]);
        ll16(A + (size_t)(m0 + srA + 16) * 96 + k0 + sc,  &As[wv * 1024 + 512]);
        ll16(B + (size_t)(n0 + srA) * 64 + k0 + sc,       &Bs[wv * 1024]);
        ll16(B + (size_t)(n0 + srA + 16) * 64 + k0 + sc,  &Bs[wv * 1024 + 512]);
        __syncthreads();

        short8 af[4], bf[4];
#pragma unroll
        for (int i = 0; i < 4; i++)
            af[i] = *(const short8*)(&As[(wm + i * 16 + lr) * BK + quad * 8]);
#pragma unroll
        for (int j = 0; j < 4; j++)
            bf[j] = *(const short8*)(&Bs[(wn + j * 16 + lr) * BK + quad * 8]);
#pragma unroll
        for (int i = 0; i < 4; i++)
#pragma unroll
            for (int j = 0; j < 4; j++)
                acc[i][j] = __builtin_amdgcn_mfma_f32_16x16x32_bf16(af[i], bf[j], acc[i][j], 0, 0, 0);
        __syncthreads();
    }

#pragma unroll
    for (int i = 0; i < 4; i++) {
        int m = m0 + wm + i * 16 + quad * 4;
#pragma unroll
        for (int j = 0; j < 4; j++) {
            int n = n0 + wn + j * 16 + lr;
            float bn = bias[n];
#pragma unroll
            for (int r = 0; r < 4; r++) {
                float x = acc[i][j][r] + bn;
                C[(size_t)(m + r) * 2048 + n] = (x > 20.f) ? x : log1pf(expf(x));
            }
        }
    }
}

// ---------------------------------------------------------------------------
// Causal depthwise conv (K=4) + bias + silu, both branches, bf16 out.
// ---------------------------------------------------------------------------
__global__ __launch_bounds__(256) void conv_silu_kernel(
    const float* __restrict__ xz,
    const float* __restrict__ w_f, const float* __restrict__ cb_f,
    const float* __restrict__ w_b, const float* __restrict__ cb_b,
    ushort_t* __restrict__ xc16)
{
    int g = blockIdx.x * 256 + threadIdx.x;
    int e  = g & 2047;
    int t  = (g >> 11) & 511;
    int b  = (g >> 20) & 3;
    int br = g >> 22;

    const float* w  = br ? w_b  : w_f;
    const float* cb = br ? cb_b : cb_f;

    float acc = cb[e];
    float4 wv = *(const float4*)(w + e * 4);
    float wk[4] = { wv.x, wv.y, wv.z, wv.w };

#pragma unroll
    for (int k = 0; k < 4; k++) {
        int tp = t - 3 + k;
        if (tp >= 0) {
            int row = br ? (511 - tp) : tp;
            acc += wk[k] * xz[((size_t)(b * 512 + row)) * 4096 + e];
        }
    }
    float s = acc / (1.f + __expf(-acc));
    xc16[g] = f2b(s);
}

// ---------------------------------------------------------------------------
// Selective scan v5: 512 blocks, 2 states/thread (n2, n2+8), el=tid>>3.
// DPP reductions (no LDS shuffles), bf16 B/C, xor-swizzled transposed staging.
// ---------------------------------------------------------------------------
__global__ __launch_bounds__(256) void scan_kernel(
    const float* __restrict__ delta,      // [2][B][L][ED] fp32
    const ushort_t* __restrict__ xc,      // [2][B][L][ED] bf16
    const ushort_t* __restrict__ dbc16,   // [2][B][L][96] bf16
    const float* __restrict__ xz,         // [B][L][4096] fp32 (z half)
    const float* __restrict__ Alog_f, const float* __restrict__ Alog_b,
    const float* __restrict__ Dp_f,   const float* __restrict__ Dp_b,
    ushort_t* __restrict__ yf, ushort_t* __restrict__ yb)
{
    const int blk = blockIdx.x;            // 0..511
    const int eg = blk & 63;
    const int b  = (blk >> 6) & 3;
    const int br = blk >> 8;
    const int e0 = eg * 32;

    const int tid = threadIdx.x;
    const int n2  = tid & 7;
    const int el  = tid >> 3;              // 0..31
    const int e   = e0 + el;

    const float* Alog = br ? Alog_b : Alog_f;
    const float* Dpp  = br ? Dp_b   : Dp_f;
    const float A0 = -__expf(Alog[e * 16 + n2]);
    const float A1 = -__expf(Alog[e * 16 + n2 + 8]);

    size_t tb = ((size_t)br * 4 + b) * 512;
    const float*    dlt  = delta + tb * 2048;
    const ushort_t* xcb  = xc    + tb * 2048;
    const ushort_t* dbcb = dbc16 + tb * 96;
    ushort_t* y = (br ? yb : yf) + (size_t)b * 512 * 2048;

    __shared__ float    sd[2][32][68];     // d[e][t^swz]
    __shared__ ushort_t sx[2][32][72];     // x[e][t^swz]
    __shared__ ushort_t sBt[2][16][72];    // B[n][t^swz] bf16
    __shared__ ushort_t sCt[2][16][72];    // C[n][t^swz] bf16
    __shared__ float    sy[64][36];        // y[t][e]

    const int stt = tid >> 2;              // 0..63 (t within chunk)
    const int seg = tid & 3;               // 8-elem column group
    const int swz = seg * 8;               // staging column xor
    const int scol = stt ^ swz;

    float4 rD0 = *(const float4*)(Dpp + e0 + seg * 8);
    float4 rD1 = *(const float4*)(Dpp + e0 + seg * 8 + 4);

    float4 rd0, rd1; uint4 rx, rbc, rx_keep;

    auto load_regs = [&](int c) {
        int t0 = c * 64;
        const float* dsrc = dlt + (size_t)(t0 + stt) * 2048 + e0 + seg * 8;
        rd0 = *(const float4*)(dsrc);
        rd1 = *(const float4*)(dsrc + 4);
        rx  = *(const uint4*)(xcb + (size_t)(t0 + stt) * 2048 + e0 + seg * 8);
        rbc = *(const uint4*)(dbcb + (size_t)(t0 + stt) * 96 + 64 + seg * 8);
    };
    auto write_lds = [&](int buf) {
        const float dv[8] = { rd0.x, rd0.y, rd0.z, rd0.w, rd1.x, rd1.y, rd1.z, rd1.w };
#pragma unroll
        for (int k = 0; k < 8; k++) sd[buf][seg * 8 + k][scol] = dv[k];
        const uint32_t xw[4] = { rx.x, rx.y, rx.z, rx.w };
#pragma unroll
        for (int k = 0; k < 4; k++) {
            sx[buf][seg * 8 + 2 * k][scol]     = (ushort_t)(xw[k] & 0xffff);
            sx[buf][seg * 8 + 2 * k + 1][scol] = (ushort_t)(xw[k] >> 16);
        }
        ushort_t* arr = (seg < 2) ? &sBt[buf][0][0] : &sCt[buf][0][0];
        const int rbase = (seg & 1) * 8;
        const uint32_t bw[4] = { rbc.x, rbc.y, rbc.z, rbc.w };
#pragma unroll
        for (int k = 0; k < 4; k++) {
            arr[(rbase + 2 * k) * 72 + scol]     = (ushort_t)(bw[k] & 0xffff);
            arr[(rbase + 2 * k + 1) * 72 + scol] = (ushort_t)(bw[k] >> 16);
        }
    };

    float h0 = 0.f, h1 = 0.f;
    const int sw = ((el >> 3) & 3) * 8;    // read-side xor (wave-uniform)

    load_regs(0);
    write_lds(0);
    rx_keep = rx;

    for (int c = 0; c < 8; ++c) {
        if (c < 7) load_regs(c + 1);
        __syncthreads();
        const int buf = c & 1;

#pragma unroll 4
        for (int tq = 0; tq < 64; tq += 4) {
            const int tc = tq ^ sw;
            float4 dv = *(const float4*)(&sd[buf][el][tc]);
            uint2  xv = *(const uint2*)(&sx[buf][el][tc]);
            uint2 bw0 = *(const uint2*)(&sBt[buf][n2][tq]);
            uint2 bw1 = *(const uint2*)(&sBt[buf][n2 + 8][tq ^ 8]);
            uint2 cw0 = *(const uint2*)(&sCt[buf][n2][tq ^ 16]);
            uint2 cw1 = *(const uint2*)(&sCt[buf][n2 + 8][tq ^ 24]);

            float x0 = b2f((ushort_t)(xv.x & 0xffff));
            float x1 = b2f((ushort_t)(xv.x >> 16));
            float x2 = b2f((ushort_t)(xv.y & 0xffff));
            float x3 = b2f((ushort_t)(xv.y >> 16));

            float B00 = b2f((ushort_t)(bw0.x & 0xffff)), B01 = b2f((ushort_t)(bw0.x >> 16));
            float B02 = b2f((ushort_t)(bw0.y & 0xffff)), B03 = b2f((ushort_t)(bw0.y >> 16));
            float B10 = b2f((ushort_t)(bw1.x & 0xffff)), B11 = b2f((ushort_t)(bw1.x >> 16));
            float B12 = b2f((ushort_t)(bw1.y & 0xffff)), B13 = b2f((ushort_t)(bw1.y >> 16));
            float C00 = b2f((ushort_t)(cw0.x & 0xffff)), C01 = b2f((ushort_t)(cw0.x >> 16));
            float C02 = b2f((ushort_t)(cw0.y & 0xffff)), C03 = b2f((ushort_t)(cw0.y >> 16));
            float C10 = b2f((ushort_t)(cw1.x & 0xffff)), C11 = b2f((ushort_t)(cw1.x >> 16));
            float C12 = b2f((ushort_t)(cw1.y & 0xffff)), C13 = b2f((ushort_t)(cw1.y >> 16));

            float e00 = __expf(dv.x * A0), e01 = __expf(dv.y * A0);
            float e02 = __expf(dv.z * A0), e03 = __expf(dv.w * A0);
            float e10 = __expf(dv.x * A1), e11 = __expf(dv.y * A1);
            float e12 = __expf(dv.z * A1), e13 = __expf(dv.w * A1);

            float dx0 = dv.x * x0, dx1 = dv.y * x1;
            float dx2 = dv.z * x2, dx3 = dv.w * x3;

            h0 = e00 * h0 + dx0 * B00;  h1 = e10 * h1 + dx0 * B10;
            float p0 = h0 * C00 + h1 * C10;
            h0 = e01 * h0 + dx1 * B01;  h1 = e11 * h1 + dx1 * B11;
            float p1 = h0 * C01 + h1 * C11;
            h0 = e02 * h0 + dx2 * B02;  h1 = e12 * h1 + dx2 * B12;
            float p2 = h0 * C02 + h1 * C12;
            h0 = e03 * h0 + dx3 * B03;  h1 = e13 * h1 + dx3 * B13;
            float p3 = h0 * C03 + h1 * C13;

            p0 = dpp_add<DPP_XOR1>(p0); p0 = dpp_add<DPP_XOR2>(p0); p0 = dpp_add<DPP_HMIR>(p0);
            p1 = dpp_add<DPP_XOR1>(p1); p1 = dpp_add<DPP_XOR2>(p1); p1 = dpp_add<DPP_HMIR>(p1);
            p2 = dpp_add<DPP_XOR1>(p2); p2 = dpp_add<DPP_XOR2>(p2); p2 = dpp_add<DPP_HMIR>(p2);
            p3 = dpp_add<DPP_XOR1>(p3); p3 = dpp_add<DPP_XOR2>(p3); p3 = dpp_add<DPP_HMIR>(p3);

            if (n2 == 0) {
                sy[tq + 0][el] = p0;
                sy[tq + 1][el] = p1;
                sy[tq + 2][el] = p2;
                sy[tq + 3][el] = p3;
            }
        }
        __syncthreads();

        // flush chunk c: gate with z*silu + D*x, store bf16
        {
            int row  = c * 64 + stt;
            int orow = br ? (511 - row) : row;
            const float* zsrc = xz + ((size_t)(b * 512 + orow)) * 4096 + 2048 + e0 + seg * 8;
            float4 z0 = *(const float4*)(zsrc);
            float4 z1 = *(const float4*)(zsrc + 4);
            float4 p0 = *(const float4*)(&sy[stt][seg * 8]);
            float4 p1 = *(const float4*)(&sy[stt][seg * 8 + 4]);
            const float pv[8] = { p0.x, p0.y, p0.z, p0.w, p1.x, p1.y, p1.z, p1.w };
            const uint32_t xw[4] = { rx_keep.x, rx_keep.y, rx_keep.z, rx_keep.w };
            float xvv[8];
#pragma unroll
            for (int k = 0; k < 4; k++) {
                xvv[2 * k]     = b2f((ushort_t)(xw[k] & 0xffff));
                xvv[2 * k + 1] = b2f((ushort_t)(xw[k] >> 16));
            }
            const float Dv[8] = { rD0.x, rD0.y, rD0.z, rD0.w, rD1.x, rD1.y, rD1.z, rD1.w };
            const float zv[8] = { z0.x, z0.y, z0.z, z0.w, z1.x, z1.y, z1.z, z1.w };
            uint32_t op[4];
#pragma unroll
            for (int k = 0; k < 4; k++) {
                float ga = (pv[2 * k]     + Dv[2 * k]     * xvv[2 * k])     *
                           (zv[2 * k]     / (1.f + __expf(-zv[2 * k])));
                float gb = (pv[2 * k + 1] + Dv[2 * k + 1] * xvv[2 * k + 1]) *
                           (zv[2 * k + 1] / (1.f + __expf(-zv[2 * k + 1])));
                op[k] = (uint32_t)f2b(ga) | ((uint32_t)f2b(gb) << 16);
            }
            *(uint4*)(y + (size_t)row * 2048 + e0 + seg * 8) =
                make_uint4(op[0], op[1], op[2], op[3]);
        }

        if (c < 7) {
            write_lds((c + 1) & 1);
            rx_keep = rx;
        }
    }
}

__global__ __launch_bounds__(256) void combine_kernel(
    const uint2* __restrict__ yf, const uint2* __restrict__ yb,
    uint2* __restrict__ yc)
{
    int g = blockIdx.x * 256 + threadIdx.x;   // 1048576 total
    int e4 = g & 511;
    int t  = (g >> 9) & 511;
    int b  = g >> 18;
    uint2 a = yf[g];
    uint2 c = yb[((size_t)(b * 512 + 511 - t)) * 512 + e4];
    uint2 o;
    o.x = (uint32_t)f2b(0.5f * (b2f((ushort_t)(a.x & 0xffff)) + b2f((ushort_t)(c.x & 0xffff)))) |
          ((uint32_t)f2b(0.5f * (b2f((ushort_t)(a.x >> 16)) + b2f((ushort_t)(c.x >> 16)))) << 16);
    o.y = (uint32_t)f2b(0.5f * (b2f((ushort_t)(a.y & 0xffff)) + b2f((ushort_t)(c.y & 0xffff)))) |
          ((uint32_t)f2b(0.5f * (b2f((ushort_t)(a.y >> 16)) + b2f((ushort_t)(c.y >> 16)))) << 16);
    yc[g] = o;
}

// ---------------------------------------------------------------------------
// Workspace layout (bytes)
// ---------------------------------------------------------------------------
static const size_t TT = 2048;  // B_SZ * L
static const size_t OFF_XZ    = 0;                          // 32MB
static const size_t OFF_XC16  = OFF_XZ    + TT*4096*4;      // 16MB
static const size_t OFF_DBC16 = OFF_XC16  + 2*TT*2048*2;    // .75MB
static const size_t OFF_DELTA = OFF_DBC16 + 2*TT*96*2;      // 32MB
static const size_t OFF_YF    = OFF_DELTA + 2*TT*2048*4;    // 8MB
static const size_t OFF_YB    = OFF_YF    + TT*2048*2;      // 8MB
static const size_t OFF_YC16  = OFF_YB    + TT*2048*2;      // 8MB
static const size_t OFF_X16   = OFF_YC16  + TT*2048*2;      // 4MB
static const size_t OFF_WIN16 = OFF_X16   + TT*1024*2;      // 8MB
static const size_t OFF_WX16  = OFF_WIN16 + 4096*1024*2;    // .75MB
static const size_t OFF_WDT16 = OFF_WX16  + 2*96*2048*2;    // .5MB
static const size_t OFF_WOUT16= OFF_WDT16 + 2*2048*64*2;    // 4MB
static const size_t OFF_PART  = OFF_WOUT16+ 1024*2048*2;    // 12.6MB

extern "C" void kernel_launch(void* const* d_in, const int* in_sizes, int n_in,
                              void* d_out, int out_size, void* d_ws, size_t ws_size,
                              hipStream_t stream) {
    const float* x       = (const float*)d_in[0];
    const float* W_in    = (const float*)d_in[1];
    const float* conv_w  = (const float*)d_in[2];
    const float* conv_b  = (const float*)d_in[3];
    const float* Wx      = (const float*)d_in[4];
    const float* Wdt     = (const float*)d_in[5];
    const float* b_dt    = (const float*)d_in[6];
    const float* A_log   = (const float*)d_in[7];
    const float* Dp      = (const float*)d_in[8];
    const float* conv_w_b= (const float*)d_in[9];
    const float* conv_b_b= (const float*)d_in[10];
    const float* Wx_b    = (const float*)d_in[11];
    const float* Wdt_b   = (const float*)d_in[12];
    const float* b_dt_b  = (const float*)d_in[13];
    const float* A_log_b = (const float*)d_in[14];
    const float* Dp_b    = (const float*)d_in[15];
    const float* W_out   = (const float*)d_in[16];
    float* out = (float*)d_out;

    char* ws = (char*)d_ws;
    float*    xz    = (float*)(ws + OFF_XZ);
    ushort_t* xc16  = (ushort_t*)(ws + OFF_XC16);
    ushort_t* dbc16 = (ushort_t*)(ws + OFF_DBC16);
    float*    delta = (float*)(ws + OFF_DELTA);
    ushort_t* yf    = (ushort_t*)(ws + OFF_YF);
    ushort_t* yb    = (ushort_t*)(ws + OFF_YB);
    ushort_t* yc16  = (ushort_t*)(ws + OFF_YC16);
    ushort_t* x16   = (ushort_t*)(ws + OFF_X16);
    ushort_t* win16 = (ushort_t*)(ws + OFF_WIN16);
    ushort_t* wx16  = (ushort_t*)(ws + OFF_WX16);
    ushort_t* wdt16 = (ushort_t*)(ws + OFF_WDT16);
    ushort_t* wout16= (ushort_t*)(ws + OFF_WOUT16);
    float*    part  = (float*)(ws + OFF_PART);

    dim3 blk(256);

    // fused fp32->bf16 casts (7 tensors, 1 launch)
    CastArgs ca;
    const int n4s[7] = {524288, 1048576, 49152, 49152, 32768, 32768, 524288};
    ca.seg[0] = { (const float4*)x,     (ushort4*)x16 };
    ca.seg[1] = { (const float4*)W_in,  (ushort4*)win16 };
    ca.seg[2] = { (const float4*)Wx,    (ushort4*)wx16 };
    ca.seg[3] = { (const float4*)Wx_b,  (ushort4*)(wx16 + 96 * 2048) };
    ca.seg[4] = { (const float4*)Wdt,   (ushort4*)wdt16 };
    ca.seg[5] = { (const float4*)Wdt_b, (ushort4*)(wdt16 + 2048 * 64) };
    ca.seg[6] = { (const float4*)W_out, (ushort4*)wout16 };
    ca.start[0] = 0;
    for (int i = 0; i < 7; i++) ca.start[i + 1] = ca.start[i] + n4s[i];
    cast_multi<<<(ca.start[7] + 255) / 256, blk, 0, stream>>>(ca);

    // G1: xz = x @ W_in^T  (2048 x 4096, K=1024)
    gemm_bt<<<dim3(32, 16), blk, 0, stream>>>(x16, 1024, win16, 1024, xz, 4096, 1024);

    // conv + silu, both branches -> bf16 x
    conv_silu_kernel<<<32768, blk, 0, stream>>>(xz, conv_w, conv_b, conv_w_b, conv_b_b, xc16);

    // G2: dbc partials (split-K=8, both branches) + reduce -> bf16
    gemm_g2<<<dim3(8, 16, 2), blk, 0, stream>>>(xc16, wx16, part);
    reduce_dbc<<<384, blk, 0, stream>>>((const float4*)part, (ushort4*)dbc16);

    // G3: delta = softplus(dbc[:, :64] @ Wdt^T + b_dt), both branches
    gemm_g3<<<dim3(16, 16, 2), blk, 0, stream>>>(dbc16, wdt16, delta, b_dt, b_dt_b);

    // selective scan + gating, both branches (v5: DPP reductions)
    scan_kernel<<<512, blk, 0, stream>>>(delta, xc16, dbc16, xz, A_log, A_log_b, Dp, Dp_b, yf, yb);

    // combine fwd + reversed bwd
    combine_kernel<<<4096, blk, 0, stream>>>((const uint2*)yf, (const uint2*)yb, (uint2*)yc16);

    // G4: out = y_comb @ W_out^T  (2048 x 1024, K=2048), BM=64 variant
    gemm_bt64<<<dim3(8, 32), blk, 0, stream>>>(yc16, 2048, wout16, 2048, out, 1024, 2048);
}

// Round 6
// 287.804 us; speedup vs baseline: 2.8060x; 1.1460x over previous
//
#include <hip/hip_runtime.h>
#include <hip/hip_bf16.h>
#include <stdint.h>

typedef unsigned short ushort_t;
typedef __attribute__((ext_vector_type(8))) short short8;
typedef __attribute__((ext_vector_type(4))) float f32x4;

__device__ __forceinline__ float b2f(ushort_t u) {
    union { uint32_t i; float f; } v; v.i = ((uint32_t)u) << 16; return v.f;
}
__device__ __forceinline__ ushort_t f2b(float f) {
    union { float f; uint32_t i; } v; v.f = f;
    uint32_t r = v.i + 0x7fff + ((v.i >> 16) & 1);
    return (ushort_t)(r >> 16);
}

// async global->LDS, 16B per lane; lds base must be wave-uniform
__device__ __forceinline__ void ll16(const ushort_t* g, ushort_t* l) {
    __builtin_amdgcn_global_load_lds(
        (const __attribute__((address_space(1))) uint32_t*)g,
        (__attribute__((address_space(3))) uint32_t*)l, 16, 0, 0);
}

// DPP cross-lane add (VALU pipe)
template <int CTRL>
__device__ __forceinline__ float dpp_add(float p) {
    int v = __builtin_amdgcn_update_dpp(0, __float_as_int(p), CTRL, 0xF, 0xF, true);
    return p + __int_as_float(v);
}
#define DPP_XOR1 0xB1
#define DPP_XOR2 0x4E
#define DPP_HMIR 0x141

// ---------------------------------------------------------------------------
// Coalesced epilogues: wave's 16x64 output group via private LDS scratch.
// Same-wave DS ops are pipe-ordered; lgkmcnt(0) guarantees read data.
// fp32: 4 rows x 256B per store instr; bf16: 4 rows x 128B.
// ---------------------------------------------------------------------------
__device__ __forceinline__ void epi_wave_f32(
    float* sw, const f32x4* accg, float* dst0, int ldc, int lane)
{
    const int quad = lane >> 4, lr = lane & 15;
#pragma unroll
    for (int j = 0; j < 4; j++)
#pragma unroll
        for (int r = 0; r < 4; r++)
            sw[(quad * 4 + r) * 64 + j * 16 + lr] = accg[j][r];
    __asm__ volatile("s_waitcnt lgkmcnt(0)" ::: "memory");
#pragma unroll
    for (int t = 0; t < 4; t++) {
        int row = t * 4 + quad;
        float4 v = *(const float4*)(&sw[row * 64 + lr * 4]);
        *(float4*)(dst0 + (size_t)row * ldc + lr * 4) = v;
    }
}

__device__ __forceinline__ void epi_wave_b16(
    float* sw, const f32x4* accg, ushort_t* dst0, int ldc, int lane)
{
    const int quad = lane >> 4, lr = lane & 15;
#pragma unroll
    for (int j = 0; j < 4; j++)
#pragma unroll
        for (int r = 0; r < 4; r++)
            sw[(quad * 4 + r) * 64 + j * 16 + lr] = accg[j][r];
    __asm__ volatile("s_waitcnt lgkmcnt(0)" ::: "memory");
#pragma unroll
    for (int t = 0; t < 4; t++) {
        int row = t * 4 + quad;
        float4 v = *(const float4*)(&sw[row * 64 + lr * 4]);
        ushort4 o; o.x = f2b(v.x); o.y = f2b(v.y); o.z = f2b(v.z); o.w = f2b(v.w);
        *(ushort4*)(dst0 + (size_t)row * ldc + lr * 4) = o;
    }
}

// ---------------------------------------------------------------------------
// Fused multi-tensor fp32 -> bf16 cast (7 segments, 1 launch)
// ---------------------------------------------------------------------------
struct CastSeg { const float4* src; ushort4* dst; };
struct CastArgs { CastSeg seg[7]; int start[8]; };

__global__ __launch_bounds__(256) void cast_multi(CastArgs a)
{
    int g = blockIdx.x * 256 + threadIdx.x;
    if (g >= a.start[7]) return;
    int s = 0;
#pragma unroll
    for (int i = 1; i < 7; i++) s += (g >= a.start[i]);
    int i = g - a.start[s];
    float4 v = a.seg[s].src[i];
    ushort4 o;
    o.x = f2b(v.x); o.y = f2b(v.y); o.z = f2b(v.z); o.w = f2b(v.w);
    a.seg[s].dst[i] = o;
}

#define BK 32

// ---------------------------------------------------------------------------
// G1: xz16 = x @ W_in^T (2048 x 4096, K=1024), bf16 out, coalesced epilogue.
// ---------------------------------------------------------------------------
__global__ __launch_bounds__(256) void gemm_g1(
    const ushort_t* __restrict__ A, int lda,
    const ushort_t* __restrict__ B, int ldb,
    ushort_t* __restrict__ Cout, int ldc, int Kd)
{
    __shared__ ushort_t As[128 * BK];
    __shared__ ushort_t Bs[128 * BK];
    __shared__ float sepi[4][1024];

    const int tid  = threadIdx.x;
    const int m0   = blockIdx.y * 128;
    const int n0   = blockIdx.x * 128;
    const int wv   = tid >> 6;
    const int lane = tid & 63;
    const int wm   = (wv >> 1) * 64;
    const int wn   = (wv & 1) * 64;
    const int lr   = lane & 15;
    const int quad = lane >> 4;

    f32x4 acc[4][4];
#pragma unroll
    for (int i = 0; i < 4; i++)
#pragma unroll
        for (int j = 0; j < 4; j++) acc[i][j] = f32x4{0.f, 0.f, 0.f, 0.f};

    const int srA = wv * 32 + (lane >> 2);
    const int scA = (lane & 3) * 8;

    for (int k0 = 0; k0 < Kd; k0 += BK) {
        ll16(A + (size_t)(m0 + srA) * lda + k0 + scA,      &As[wv * 1024]);
        ll16(A + (size_t)(m0 + srA + 16) * lda + k0 + scA, &As[wv * 1024 + 512]);
        ll16(B + (size_t)(n0 + srA) * ldb + k0 + scA,      &Bs[wv * 1024]);
        ll16(B + (size_t)(n0 + srA + 16) * ldb + k0 + scA, &Bs[wv * 1024 + 512]);
        __syncthreads();

        short8 af[4], bf[4];
#pragma unroll
        for (int i = 0; i < 4; i++)
            af[i] = *(const short8*)(&As[(wm + i * 16 + lr) * BK + quad * 8]);
#pragma unroll
        for (int j = 0; j < 4; j++)
            bf[j] = *(const short8*)(&Bs[(wn + j * 16 + lr) * BK + quad * 8]);
#pragma unroll
        for (int i = 0; i < 4; i++)
#pragma unroll
            for (int j = 0; j < 4; j++)
                acc[i][j] = __builtin_amdgcn_mfma_f32_16x16x32_bf16(af[i], bf[j], acc[i][j], 0, 0, 0);
        __syncthreads();
    }

#pragma unroll
    for (int g = 0; g < 4; g++)
        epi_wave_b16(sepi[wv], acc[g],
                     Cout + (size_t)(m0 + wm + g * 16) * ldc + n0 + wn, ldc, lane);
}

// ---------------------------------------------------------------------------
// G4: out = y @ W_out^T (2048 x 1024, K=2048), fp32 out, BM=64 variant.
// ---------------------------------------------------------------------------
__global__ __launch_bounds__(256) void gemm_g4(
    const ushort_t* __restrict__ A, int lda,
    const ushort_t* __restrict__ B, int ldb,
    float* __restrict__ Cout, int ldc, int Kd)
{
    __shared__ ushort_t As[64 * BK];
    __shared__ ushort_t Bs[128 * BK];
    __shared__ float sepi[4][1024];

    const int tid  = threadIdx.x;
    const int m0   = blockIdx.y * 64;
    const int n0   = blockIdx.x * 128;
    const int wv   = tid >> 6;
    const int lane = tid & 63;
    const int wm   = (wv >> 1) * 32;
    const int wn   = (wv & 1) * 64;
    const int lr   = lane & 15;
    const int quad = lane >> 4;

    f32x4 acc[2][4];
#pragma unroll
    for (int i = 0; i < 2; i++)
#pragma unroll
        for (int j = 0; j < 4; j++) acc[i][j] = f32x4{0.f, 0.f, 0.f, 0.f};

    const int srA = wv * 16 + (lane >> 2);
    const int srB = wv * 32 + (lane >> 2);
    const int sc  = (lane & 3) * 8;

    for (int k0 = 0; k0 < Kd; k0 += BK) {
        ll16(A + (size_t)(m0 + srA) * lda + k0 + sc,      &As[wv * 512]);
        ll16(B + (size_t)(n0 + srB) * ldb + k0 + sc,      &Bs[wv * 1024]);
        ll16(B + (size_t)(n0 + srB + 16) * ldb + k0 + sc, &Bs[wv * 1024 + 512]);
        __syncthreads();

        short8 af[2], bf[4];
#pragma unroll
        for (int i = 0; i < 2; i++)
            af[i] = *(const short8*)(&As[(wm + i * 16 + lr) * BK + quad * 8]);
#pragma unroll
        for (int j = 0; j < 4; j++)
            bf[j] = *(const short8*)(&Bs[(wn + j * 16 + lr) * BK + quad * 8]);
#pragma unroll
        for (int i = 0; i < 2; i++)
#pragma unroll
            for (int j = 0; j < 4; j++)
                acc[i][j] = __builtin_amdgcn_mfma_f32_16x16x32_bf16(af[i], bf[j], acc[i][j], 0, 0, 0);
        __syncthreads();
    }

#pragma unroll
    for (int g = 0; g < 2; g++)
        epi_wave_f32(sepi[wv], acc[g],
                     Cout + (size_t)(m0 + wm + g * 16) * ldc + n0 + wn, ldc, lane);
}

// ---------------------------------------------------------------------------
// G2: dbc partials. grid (SK=8, M/128=16, br=2). N=96, guarded coalesced epi.
// ---------------------------------------------------------------------------
__global__ __launch_bounds__(256) void gemm_g2(
    const ushort_t* __restrict__ xc, const ushort_t* __restrict__ wx,
    float* __restrict__ part)
{
    __shared__ ushort_t As[128 * BK];
    __shared__ ushort_t Bs[128 * BK];
    __shared__ float sepi[4][1024];

    const int sk = blockIdx.x, mb = blockIdx.y, br = blockIdx.z;
    const ushort_t* A = xc + (size_t)br * 2048 * 2048;
    const ushort_t* B = wx + (size_t)br * 96 * 2048;
    float* C = part + (size_t)(sk * 2 + br) * 2048 * 96;
    const int m0 = mb * 128;
    const int kb = sk * 256;

    const int tid  = threadIdx.x;
    const int wv   = tid >> 6;
    const int lane = tid & 63;
    const int wm   = (wv >> 1) * 64;
    const int wn   = (wv & 1) * 64;
    const int lr   = lane & 15;
    const int quad = lane >> 4;

    f32x4 acc[4][4];
#pragma unroll
    for (int i = 0; i < 4; i++)
#pragma unroll
        for (int j = 0; j < 4; j++) acc[i][j] = f32x4{0.f, 0.f, 0.f, 0.f};

    const int srA = wv * 32 + (lane >> 2);
    const int sc  = (lane & 3) * 8;

    for (int k0 = kb; k0 < kb + 256; k0 += BK) {
        ll16(A + (size_t)(m0 + srA) * 2048 + k0 + sc,      &As[wv * 1024]);
        ll16(A + (size_t)(m0 + srA + 16) * 2048 + k0 + sc, &As[wv * 1024 + 512]);
        ll16(B + (size_t)(srA) * 2048 + k0 + sc,           &Bs[wv * 1024]);
        ll16(B + (size_t)(srA + 16) * 2048 + k0 + sc,      &Bs[wv * 1024 + 512]);
        __syncthreads();

        short8 af[4], bf[4];
#pragma unroll
        for (int i = 0; i < 4; i++)
            af[i] = *(const short8*)(&As[(wm + i * 16 + lr) * BK + quad * 8]);
#pragma unroll
        for (int j = 0; j < 4; j++)
            bf[j] = *(const short8*)(&Bs[(wn + j * 16 + lr) * BK + quad * 8]);
#pragma unroll
        for (int i = 0; i < 4; i++)
#pragma unroll
            for (int j = 0; j < 4; j++)
                acc[i][j] = __builtin_amdgcn_mfma_f32_16x16x32_bf16(af[i], bf[j], acc[i][j], 0, 0, 0);
        __syncthreads();
    }

    // guarded coalesced epilogue (cols wn..wn+63, keep < 96)
    float* sw = sepi[wv];
#pragma unroll
    for (int g = 0; g < 4; g++) {
#pragma unroll
        for (int j = 0; j < 4; j++)
#pragma unroll
            for (int r = 0; r < 4; r++)
                sw[(quad * 4 + r) * 64 + j * 16 + lr] = acc[g][j][r];
        __asm__ volatile("s_waitcnt lgkmcnt(0)" ::: "memory");
        int col = wn + lr * 4;
#pragma unroll
        for (int t = 0; t < 4; t++) {
            int row = t * 4 + quad;
            if (col < 96) {
                float4 v = *(const float4*)(&sw[row * 64 + lr * 4]);
                *(float4*)(C + (size_t)(m0 + wm + g * 16 + row) * 96 + col) = v;
            }
        }
    }
}

__global__ __launch_bounds__(256) void reduce_dbc(
    const float4* __restrict__ part, ushort4* __restrict__ dbc16)
{
    int g = blockIdx.x * 256 + threadIdx.x;   // 98304 total
    const int S = 2 * 2048 * 96 / 4;
    float4 r = part[g];
#pragma unroll
    for (int i = 1; i < 8; i++) {
        float4 p = part[g + i * S];
        r.x += p.x; r.y += p.y; r.z += p.z; r.w += p.w;
    }
    ushort4 o; o.x = f2b(r.x); o.y = f2b(r.y); o.z = f2b(r.z); o.w = f2b(r.w);
    dbc16[g] = o;
}

// ---------------------------------------------------------------------------
// G3: delta16 = softplus(dbc[:, :64] @ Wdt^T + b_dt), bf16 out, fast softplus.
// ---------------------------------------------------------------------------
__global__ __launch_bounds__(256) void gemm_g3(
    const ushort_t* __restrict__ dbc16, const ushort_t* __restrict__ wdt,
    ushort_t* __restrict__ delta,
    const float* __restrict__ bdt_f, const float* __restrict__ bdt_b)
{
    __shared__ ushort_t As[128 * BK];
    __shared__ ushort_t Bs[128 * BK];
    __shared__ float sepi[4][1024];

    const int br = blockIdx.z;
    const ushort_t* A = dbc16 + (size_t)br * 2048 * 96;
    const ushort_t* B = wdt + (size_t)br * 2048 * 64;
    ushort_t* C = delta + (size_t)br * 2048 * 2048;
    const float* bias = br ? bdt_b : bdt_f;

    const int tid  = threadIdx.x;
    const int m0   = blockIdx.y * 128;
    const int n0   = blockIdx.x * 128;
    const int wv   = tid >> 6;
    const int lane = tid & 63;
    const int wm   = (wv >> 1) * 64;
    const int wn   = (wv & 1) * 64;
    const int lr   = lane & 15;
    const int quad = lane >> 4;

    f32x4 acc[4][4];
#pragma unroll
    for (int i = 0; i < 4; i++)
#pragma unroll
        for (int j = 0; j < 4; j++) acc[i][j] = f32x4{0.f, 0.f, 0.f, 0.f};

    const int srA = wv * 32 + (lane >> 2);
    const int sc  = (lane & 3) * 8;

    for (int k0 = 0; k0 < 64; k0 += BK) {
        ll16(A + (size_t)(m0 + srA) * 96 + k0 + sc,       &As[wv * 1024]);
        ll16(A + (size_t)(m0 + srA + 16) * 96 + k0 + sc,  &As[wv * 1024 + 512]);
        ll16(B + (size_t)(n0 + srA) * 64 + k0 + sc,       &Bs[wv * 1024]);
        ll16(B + (size_t)(n0 + srA + 16) * 64 + k0 + sc,  &Bs[wv * 1024 + 512]);
        __syncthreads();

        short8 af[4], bf[4];
#pragma unroll
        for (int i = 0; i < 4; i++)
            af[i] = *(const short8*)(&As[(wm + i * 16 + lr) * BK + quad * 8]);
#pragma unroll
        for (int j = 0; j < 4; j++)
            bf[j] = *(const short8*)(&Bs[(wn + j * 16 + lr) * BK + quad * 8]);
#pragma unroll
        for (int i = 0; i < 4; i++)
#pragma unroll
            for (int j = 0; j < 4; j++)
                acc[i][j] = __builtin_amdgcn_mfma_f32_16x16x32_bf16(af[i], bf[j], acc[i][j], 0, 0, 0);
        __syncthreads();
    }

    // fused bias + fast branch-free softplus
    float bn[4];
#pragma unroll
    for (int j = 0; j < 4; j++) bn[j] = bias[n0 + wn + j * 16 + lr];
#pragma unroll
    for (int g = 0; g < 4; g++)
#pragma unroll
        for (int j = 0; j < 4; j++)
#pragma unroll
            for (int r = 0; r < 4; r++) {
                float x = acc[g][j][r] + bn[j];
                float sp = fmaxf(x, 0.f) + __logf(1.f + __expf(-fabsf(x)));
                acc[g][j][r] = sp;
            }

#pragma unroll
    for (int g = 0; g < 4; g++)
        epi_wave_b16(sepi[wv], acc[g],
                     C + (size_t)(m0 + wm + g * 16) * 2048 + n0 + wn, 2048, lane);
}

// ---------------------------------------------------------------------------
// Causal depthwise conv (K=4) + bias + silu, both branches, bf16 in/out.
// ---------------------------------------------------------------------------
__global__ __launch_bounds__(256) void conv_silu_kernel(
    const ushort_t* __restrict__ xz,
    const float* __restrict__ w_f, const float* __restrict__ cb_f,
    const float* __restrict__ w_b, const float* __restrict__ cb_b,
    ushort_t* __restrict__ xc16)
{
    int g = blockIdx.x * 256 + threadIdx.x;
    int e  = g & 2047;
    int t  = (g >> 11) & 511;
    int b  = (g >> 20) & 3;
    int br = g >> 22;

    const float* w  = br ? w_b  : w_f;
    const float* cb = br ? cb_b : cb_f;

    float acc = cb[e];
    float4 wv = *(const float4*)(w + e * 4);
    float wk[4] = { wv.x, wv.y, wv.z, wv.w };

#pragma unroll
    for (int k = 0; k < 4; k++) {
        int tp = t - 3 + k;
        if (tp >= 0) {
            int row = br ? (511 - tp) : tp;
            acc += wk[k] * b2f(xz[((size_t)(b * 512 + row)) * 4096 + e]);
        }
    }
    float s = acc / (1.f + __expf(-acc));
    xc16[g] = f2b(s);
}

// ---------------------------------------------------------------------------
// Selective scan v6: bf16 delta/z inputs; otherwise v5 (DPP reductions).
// ---------------------------------------------------------------------------
__global__ __launch_bounds__(256) void scan_kernel(
    const ushort_t* __restrict__ delta,   // [2][B][L][ED] bf16
    const ushort_t* __restrict__ xc,      // [2][B][L][ED] bf16
    const ushort_t* __restrict__ dbc16,   // [2][B][L][96] bf16
    const ushort_t* __restrict__ xz,      // [B][L][4096] bf16 (z half)
    const float* __restrict__ Alog_f, const float* __restrict__ Alog_b,
    const float* __restrict__ Dp_f,   const float* __restrict__ Dp_b,
    ushort_t* __restrict__ yf, ushort_t* __restrict__ yb)
{
    const int blk = blockIdx.x;            // 0..511
    const int eg = blk & 63;
    const int b  = (blk >> 6) & 3;
    const int br = blk >> 8;
    const int e0 = eg * 32;

    const int tid = threadIdx.x;
    const int n2  = tid & 7;
    const int el  = tid >> 3;              // 0..31
    const int e   = e0 + el;

    const float* Alog = br ? Alog_b : Alog_f;
    const float* Dpp  = br ? Dp_b   : Dp_f;
    const float A0 = -__expf(Alog[e * 16 + n2]);
    const float A1 = -__expf(Alog[e * 16 + n2 + 8]);

    size_t tb = ((size_t)br * 4 + b) * 512;
    const ushort_t* dlt  = delta + tb * 2048;
    const ushort_t* xcb  = xc    + tb * 2048;
    const ushort_t* dbcb = dbc16 + tb * 96;
    ushort_t* y = (br ? yb : yf) + (size_t)b * 512 * 2048;

    __shared__ float    sd[2][32][68];     // d[e][t^swz]
    __shared__ ushort_t sx[2][32][72];     // x[e][t^swz]
    __shared__ ushort_t sBt[2][16][72];    // B[n][t^swz] bf16
    __shared__ ushort_t sCt[2][16][72];    // C[n][t^swz] bf16
    __shared__ float    sy[64][36];        // y[t][e]

    const int stt = tid >> 2;              // 0..63 (t within chunk)
    const int seg = tid & 3;               // 8-elem column group
    const int swz = seg * 8;
    const int scol = stt ^ swz;

    float4 rD0 = *(const float4*)(Dpp + e0 + seg * 8);
    float4 rD1 = *(const float4*)(Dpp + e0 + seg * 8 + 4);

    uint4 rdx, rx, rbc, rx_keep;

    auto load_regs = [&](int c) {
        int t0 = c * 64;
        rdx = *(const uint4*)(dlt + (size_t)(t0 + stt) * 2048 + e0 + seg * 8);
        rx  = *(const uint4*)(xcb + (size_t)(t0 + stt) * 2048 + e0 + seg * 8);
        rbc = *(const uint4*)(dbcb + (size_t)(t0 + stt) * 96 + 64 + seg * 8);
    };
    auto write_lds = [&](int buf) {
        const uint32_t dw[4] = { rdx.x, rdx.y, rdx.z, rdx.w };
#pragma unroll
        for (int k = 0; k < 4; k++) {
            sd[buf][seg * 8 + 2 * k][scol]     = b2f((ushort_t)(dw[k] & 0xffff));
            sd[buf][seg * 8 + 2 * k + 1][scol] = b2f((ushort_t)(dw[k] >> 16));
        }
        const uint32_t xw[4] = { rx.x, rx.y, rx.z, rx.w };
#pragma unroll
        for (int k = 0; k < 4; k++) {
            sx[buf][seg * 8 + 2 * k][scol]     = (ushort_t)(xw[k] & 0xffff);
            sx[buf][seg * 8 + 2 * k + 1][scol] = (ushort_t)(xw[k] >> 16);
        }
        ushort_t* arr = (seg < 2) ? &sBt[buf][0][0] : &sCt[buf][0][0];
        const int rbase = (seg & 1) * 8;
        const uint32_t bw[4] = { rbc.x, rbc.y, rbc.z, rbc.w };
#pragma unroll
        for (int k = 0; k < 4; k++) {
            arr[(rbase + 2 * k) * 72 + scol]     = (ushort_t)(bw[k] & 0xffff);
            arr[(rbase + 2 * k + 1) * 72 + scol] = (ushort_t)(bw[k] >> 16);
        }
    };

    float h0 = 0.f, h1 = 0.f;
    const int sw = ((el >> 3) & 3) * 8;    // read-side xor (wave-uniform)

    load_regs(0);
    write_lds(0);
    rx_keep = rx;

    for (int c = 0; c < 8; ++c) {
        if (c < 7) load_regs(c + 1);
        __syncthreads();
        const int buf = c & 1;

#pragma unroll 4
        for (int tq = 0; tq < 64; tq += 4) {
            const int tc = tq ^ sw;
            float4 dv = *(const float4*)(&sd[buf][el][tc]);
            uint2  xv = *(const uint2*)(&sx[buf][el][tc]);
            uint2 bw0 = *(const uint2*)(&sBt[buf][n2][tq]);
            uint2 bw1 = *(const uint2*)(&sBt[buf][n2 + 8][tq ^ 8]);
            uint2 cw0 = *(const uint2*)(&sCt[buf][n2][tq ^ 16]);
            uint2 cw1 = *(const uint2*)(&sCt[buf][n2 + 8][tq ^ 24]);

            float x0 = b2f((ushort_t)(xv.x & 0xffff));
            float x1 = b2f((ushort_t)(xv.x >> 16));
            float x2 = b2f((ushort_t)(xv.y & 0xffff));
            float x3 = b2f((ushort_t)(xv.y >> 16));

            float B00 = b2f((ushort_t)(bw0.x & 0xffff)), B01 = b2f((ushort_t)(bw0.x >> 16));
            float B02 = b2f((ushort_t)(bw0.y & 0xffff)), B03 = b2f((ushort_t)(bw0.y >> 16));
            float B10 = b2f((ushort_t)(bw1.x & 0xffff)), B11 = b2f((ushort_t)(bw1.x >> 16));
            float B12 = b2f((ushort_t)(bw1.y & 0xffff)), B13 = b2f((ushort_t)(bw1.y >> 16));
            float C00 = b2f((ushort_t)(cw0.x & 0xffff)), C01 = b2f((ushort_t)(cw0.x >> 16));
            float C02 = b2f((ushort_t)(cw0.y & 0xffff)), C03 = b2f((ushort_t)(cw0.y >> 16));
            float C10 = b2f((ushort_t)(cw1.x & 0xffff)), C11 = b2f((ushort_t)(cw1.x >> 16));
            float C12 = b2f((ushort_t)(cw1.y & 0xffff)), C13 = b2f((ushort_t)(cw1.y >> 16));

            float e00 = __expf(dv.x * A0), e01 = __expf(dv.y * A0);
            float e02 = __expf(dv.z * A0), e03 = __expf(dv.w * A0);
            float e10 = __expf(dv.x * A1), e11 = __expf(dv.y * A1);
            float e12 = __expf(dv.z * A1), e13 = __expf(dv.w * A1);

            float dx0 = dv.x * x0, dx1 = dv.y * x1;
            float dx2 = dv.z * x2, dx3 = dv.w * x3;

            h0 = e00 * h0 + dx0 * B00;  h1 = e10 * h1 + dx0 * B10;
            float p0 = h0 * C00 + h1 * C10;
            h0 = e01 * h0 + dx1 * B01;  h1 = e11 * h1 + dx1 * B11;
            float p1 = h0 * C01 + h1 * C11;
            h0 = e02 * h0 + dx2 * B02;  h1 = e12 * h1 + dx2 * B12;
            float p2 = h0 * C02 + h1 * C12;
            h0 = e03 * h0 + dx3 * B03;  h1 = e13 * h1 + dx3 * B13;
            float p3 = h0 * C03 + h1 * C13;

            p0 = dpp_add<DPP_XOR1>(p0); p0 = dpp_add<DPP_XOR2>(p0); p0 = dpp_add<DPP_HMIR>(p0);
            p1 = dpp_add<DPP_XOR1>(p1); p1 = dpp_add<DPP_XOR2>(p1); p1 = dpp_add<DPP_HMIR>(p1);
            p2 = dpp_add<DPP_XOR1>(p2); p2 = dpp_add<DPP_XOR2>(p2); p2 = dpp_add<DPP_HMIR>(p2);
            p3 = dpp_add<DPP_XOR1>(p3); p3 = dpp_add<DPP_XOR2>(p3); p3 = dpp_add<DPP_HMIR>(p3);

            if (n2 == 0) {
                sy[tq + 0][el] = p0;
                sy[tq + 1][el] = p1;
                sy[tq + 2][el] = p2;
                sy[tq + 3][el] = p3;
            }
        }
        __syncthreads();

        // flush chunk c: gate with z*silu + D*x, store bf16
        {
            int row  = c * 64 + stt;
            int orow = br ? (511 - row) : row;
            const ushort_t* zsrc = xz + ((size_t)(b * 512 + orow)) * 4096 + 2048 + e0 + seg * 8;
            uint4 zr = *(const uint4*)(zsrc);
            const uint32_t zw[4] = { zr.x, zr.y, zr.z, zr.w };
            float zv[8];
#pragma unroll
            for (int k = 0; k < 4; k++) {
                zv[2 * k]     = b2f((ushort_t)(zw[k] & 0xffff));
                zv[2 * k + 1] = b2f((ushort_t)(zw[k] >> 16));
            }
            float4 p0 = *(const float4*)(&sy[stt][seg * 8]);
            float4 p1 = *(const float4*)(&sy[stt][seg * 8 + 4]);
            const float pv[8] = { p0.x, p0.y, p0.z, p0.w, p1.x, p1.y, p1.z, p1.w };
            const uint32_t xw[4] = { rx_keep.x, rx_keep.y, rx_keep.z, rx_keep.w };
            float xvv[8];
#pragma unroll
            for (int k = 0; k < 4; k++) {
                xvv[2 * k]     = b2f((ushort_t)(xw[k] & 0xffff));
                xvv[2 * k + 1] = b2f((ushort_t)(xw[k] >> 16));
            }
            const float Dv[8] = { rD0.x, rD0.y, rD0.z, rD0.w, rD1.x, rD1.y, rD1.z, rD1.w };
            uint32_t op[4];
#pragma unroll
            for (int k = 0; k < 4; k++) {
                float ga = (pv[2 * k]     + Dv[2 * k]     * xvv[2 * k])     *
                           (zv[2 * k]     / (1.f + __expf(-zv[2 * k])));
                float gb = (pv[2 * k + 1] + Dv[2 * k + 1] * xvv[2 * k + 1]) *
                           (zv[2 * k + 1] / (1.f + __expf(-zv[2 * k + 1])));
                op[k] = (uint32_t)f2b(ga) | ((uint32_t)f2b(gb) << 16);
            }
            *(uint4*)(y + (size_t)row * 2048 + e0 + seg * 8) =
                make_uint4(op[0], op[1], op[2], op[3]);
        }

        if (c < 7) {
            write_lds((c + 1) & 1);
            rx_keep = rx;
        }
    }
}

__global__ __launch_bounds__(256) void combine_kernel(
    const uint2* __restrict__ yf, const uint2* __restrict__ yb,
    uint2* __restrict__ yc)
{
    int g = blockIdx.x * 256 + threadIdx.x;   // 1048576 total
    int e4 = g & 511;
    int t  = (g >> 9) & 511;
    int b  = g >> 18;
    uint2 a = yf[g];
    uint2 c = yb[((size_t)(b * 512 + 511 - t)) * 512 + e4];
    uint2 o;
    o.x = (uint32_t)f2b(0.5f * (b2f((ushort_t)(a.x & 0xffff)) + b2f((ushort_t)(c.x & 0xffff)))) |
          ((uint32_t)f2b(0.5f * (b2f((ushort_t)(a.x >> 16)) + b2f((ushort_t)(c.x >> 16)))) << 16);
    o.y = (uint32_t)f2b(0.5f * (b2f((ushort_t)(a.y & 0xffff)) + b2f((ushort_t)(c.y & 0xffff)))) |
          ((uint32_t)f2b(0.5f * (b2f((ushort_t)(a.y >> 16)) + b2f((ushort_t)(c.y >> 16)))) << 16);
    yc[g] = o;
}

// ---------------------------------------------------------------------------
// Workspace layout (bytes)
// ---------------------------------------------------------------------------
static const size_t TT = 2048;  // B_SZ * L
static const size_t OFF_XZ16  = 0;                          // T*4096 bf16 16MB
static const size_t OFF_XC16  = OFF_XZ16  + TT*4096*2;      // 16MB
static const size_t OFF_DBC16 = OFF_XC16  + 2*TT*2048*2;    // .75MB
static const size_t OFF_DELTA = OFF_DBC16 + 2*TT*96*2;      // bf16 16MB
static const size_t OFF_YF    = OFF_DELTA + 2*TT*2048*2;    // 8MB
static const size_t OFF_YB    = OFF_YF    + TT*2048*2;      // 8MB
static const size_t OFF_YC16  = OFF_YB    + TT*2048*2;      // 8MB
static const size_t OFF_X16   = OFF_YC16  + TT*2048*2;      // 4MB
static const size_t OFF_WIN16 = OFF_X16   + TT*1024*2;      // 8MB
static const size_t OFF_WX16  = OFF_WIN16 + 4096*1024*2;    // .75MB
static const size_t OFF_WDT16 = OFF_WX16  + 2*96*2048*2;    // .5MB
static const size_t OFF_WOUT16= OFF_WDT16 + 2*2048*64*2;    // 4MB
static const size_t OFF_PART  = OFF_WOUT16+ 1024*2048*2;    // 12.6MB

extern "C" void kernel_launch(void* const* d_in, const int* in_sizes, int n_in,
                              void* d_out, int out_size, void* d_ws, size_t ws_size,
                              hipStream_t stream) {
    const float* x       = (const float*)d_in[0];
    const float* W_in    = (const float*)d_in[1];
    const float* conv_w  = (const float*)d_in[2];
    const float* conv_b  = (const float*)d_in[3];
    const float* Wx      = (const float*)d_in[4];
    const float* Wdt     = (const float*)d_in[5];
    const float* b_dt    = (const float*)d_in[6];
    const float* A_log   = (const float*)d_in[7];
    const float* Dp      = (const float*)d_in[8];
    const float* conv_w_b= (const float*)d_in[9];
    const float* conv_b_b= (const float*)d_in[10];
    const float* Wx_b    = (const float*)d_in[11];
    const float* Wdt_b   = (const float*)d_in[12];
    const float* b_dt_b  = (const float*)d_in[13];
    const float* A_log_b = (const float*)d_in[14];
    const float* Dp_b    = (const float*)d_in[15];
    const float* W_out   = (const float*)d_in[16];
    float* out = (float*)d_out;

    char* ws = (char*)d_ws;
    ushort_t* xz16  = (ushort_t*)(ws + OFF_XZ16);
    ushort_t* xc16  = (ushort_t*)(ws + OFF_XC16);
    ushort_t* dbc16 = (ushort_t*)(ws + OFF_DBC16);
    ushort_t* delta = (ushort_t*)(ws + OFF_DELTA);
    ushort_t* yf    = (ushort_t*)(ws + OFF_YF);
    ushort_t* yb    = (ushort_t*)(ws + OFF_YB);
    ushort_t* yc16  = (ushort_t*)(ws + OFF_YC16);
    ushort_t* x16   = (ushort_t*)(ws + OFF_X16);
    ushort_t* win16 = (ushort_t*)(ws + OFF_WIN16);
    ushort_t* wx16  = (ushort_t*)(ws + OFF_WX16);
    ushort_t* wdt16 = (ushort_t*)(ws + OFF_WDT16);
    ushort_t* wout16= (ushort_t*)(ws + OFF_WOUT16);
    float*    part  = (float*)(ws + OFF_PART);

    dim3 blk(256);

    // fused fp32->bf16 casts (7 tensors, 1 launch)
    CastArgs ca;
    const int n4s[7] = {524288, 1048576, 49152, 49152, 32768, 32768, 524288};
    ca.seg[0] = { (const float4*)x,     (ushort4*)x16 };
    ca.seg[1] = { (const float4*)W_in,  (ushort4*)win16 };
    ca.seg[2] = { (const float4*)Wx,    (ushort4*)wx16 };
    ca.seg[3] = { (const float4*)Wx_b,  (ushort4*)(wx16 + 96 * 2048) };
    ca.seg[4] = { (const float4*)Wdt,   (ushort4*)wdt16 };
    ca.seg[5] = { (const float4*)Wdt_b, (ushort4*)(wdt16 + 2048 * 64) };
    ca.seg[6] = { (const float4*)W_out, (ushort4*)wout16 };
    ca.start[0] = 0;
    for (int i = 0; i < 7; i++) ca.start[i + 1] = ca.start[i] + n4s[i];
    cast_multi<<<(ca.start[7] + 255) / 256, blk, 0, stream>>>(ca);

    // G1: xz16 = x @ W_in^T  (2048 x 4096, K=1024), bf16 out
    gemm_g1<<<dim3(32, 16), blk, 0, stream>>>(x16, 1024, win16, 1024, xz16, 4096, 1024);

    // conv + silu, both branches -> bf16 x
    conv_silu_kernel<<<32768, blk, 0, stream>>>(xz16, conv_w, conv_b, conv_w_b, conv_b_b, xc16);

    // G2: dbc partials (split-K=8, both branches) + reduce -> bf16
    gemm_g2<<<dim3(8, 16, 2), blk, 0, stream>>>(xc16, wx16, part);
    reduce_dbc<<<384, blk, 0, stream>>>((const float4*)part, (ushort4*)dbc16);

    // G3: delta16 = softplus(dbc[:, :64] @ Wdt^T + b_dt), bf16 out
    gemm_g3<<<dim3(16, 16, 2), blk, 0, stream>>>(dbc16, wdt16, delta, b_dt, b_dt_b);

    // selective scan + gating, both branches
    scan_kernel<<<512, blk, 0, stream>>>(delta, xc16, dbc16, xz16, A_log, A_log_b, Dp, Dp_b, yf, yb);

    // combine fwd + reversed bwd
    combine_kernel<<<4096, blk, 0, stream>>>((const uint2*)yf, (const uint2*)yb, (uint2*)yc16);

    // G4: out = y_comb @ W_out^T  (2048 x 1024, K=2048), fp32 out
    gemm_g4<<<dim3(8, 32), blk, 0, stream>>>(yc16, 2048, wout16, 2048, out, 1024, 2048);
}

// Round 7
// 281.851 us; speedup vs baseline: 2.8653x; 1.0211x over previous
//
#include <hip/hip_runtime.h>
#include <hip/hip_bf16.h>
#include <stdint.h>

typedef unsigned short ushort_t;
typedef __attribute__((ext_vector_type(8))) short short8;
typedef __attribute__((ext_vector_type(4))) float f32x4;

__device__ __forceinline__ float b2f(ushort_t u) {
    union { uint32_t i; float f; } v; v.i = ((uint32_t)u) << 16; return v.f;
}
__device__ __forceinline__ ushort_t f2b(float f) {
    union { float f; uint32_t i; } v; v.f = f;
    uint32_t r = v.i + 0x7fff + ((v.i >> 16) & 1);
    return (ushort_t)(r >> 16);
}

#if __has_builtin(__builtin_amdgcn_exp2f)
#define EXP2(x) __builtin_amdgcn_exp2f(x)
#else
#define EXP2(x) __expf((x) * 0.69314718056f)
#endif

// async global->LDS, 16B per lane; lds base must be wave-uniform
__device__ __forceinline__ void ll16(const ushort_t* g, ushort_t* l) {
    __builtin_amdgcn_global_load_lds(
        (const __attribute__((address_space(1))) uint32_t*)g,
        (__attribute__((address_space(3))) uint32_t*)l, 16, 0, 0);
}

// DPP cross-lane add (VALU pipe)
template <int CTRL>
__device__ __forceinline__ float dpp_add(float p) {
    int v = __builtin_amdgcn_update_dpp(0, __float_as_int(p), CTRL, 0xF, 0xF, true);
    return p + __int_as_float(v);
}
#define DPP_XOR1 0xB1
#define DPP_XOR2 0x4E
#define DPP_HMIR 0x141

// ---------------------------------------------------------------------------
// Coalesced epilogues: wave's 16x64 output group via private LDS scratch.
// ---------------------------------------------------------------------------
__device__ __forceinline__ void epi_wave_f32(
    float* sw, const f32x4* accg, float* dst0, int ldc, int lane)
{
    const int quad = lane >> 4, lr = lane & 15;
#pragma unroll
    for (int j = 0; j < 4; j++)
#pragma unroll
        for (int r = 0; r < 4; r++)
            sw[(quad * 4 + r) * 64 + j * 16 + lr] = accg[j][r];
    __asm__ volatile("s_waitcnt lgkmcnt(0)" ::: "memory");
#pragma unroll
    for (int t = 0; t < 4; t++) {
        int row = t * 4 + quad;
        float4 v = *(const float4*)(&sw[row * 64 + lr * 4]);
        *(float4*)(dst0 + (size_t)row * ldc + lr * 4) = v;
    }
}

__device__ __forceinline__ void epi_wave_b16(
    float* sw, const f32x4* accg, ushort_t* dst0, int ldc, int lane)
{
    const int quad = lane >> 4, lr = lane & 15;
#pragma unroll
    for (int j = 0; j < 4; j++)
#pragma unroll
        for (int r = 0; r < 4; r++)
            sw[(quad * 4 + r) * 64 + j * 16 + lr] = accg[j][r];
    __asm__ volatile("s_waitcnt lgkmcnt(0)" ::: "memory");
#pragma unroll
    for (int t = 0; t < 4; t++) {
        int row = t * 4 + quad;
        float4 v = *(const float4*)(&sw[row * 64 + lr * 4]);
        ushort4 o; o.x = f2b(v.x); o.y = f2b(v.y); o.z = f2b(v.z); o.w = f2b(v.w);
        *(ushort4*)(dst0 + (size_t)row * ldc + lr * 4) = o;
    }
}

// ---------------------------------------------------------------------------
// Fused multi-tensor fp32 -> bf16 cast (7 segments, 1 launch)
// ---------------------------------------------------------------------------
struct CastSeg { const float4* src; ushort4* dst; };
struct CastArgs { CastSeg seg[7]; int start[8]; };

__global__ __launch_bounds__(256) void cast_multi(CastArgs a)
{
    int g = blockIdx.x * 256 + threadIdx.x;
    if (g >= a.start[7]) return;
    int s = 0;
#pragma unroll
    for (int i = 1; i < 7; i++) s += (g >= a.start[i]);
    int i = g - a.start[s];
    float4 v = a.seg[s].src[i];
    ushort4 o;
    o.x = f2b(v.x); o.y = f2b(v.y); o.z = f2b(v.z); o.w = f2b(v.w);
    a.seg[s].dst[i] = o;
}

#define BK 32

// ---------------------------------------------------------------------------
// G1: xz16 = x @ W_in^T (2048 x 4096, K=1024), bf16 out, coalesced epilogue.
// ---------------------------------------------------------------------------
__global__ __launch_bounds__(256) void gemm_g1(
    const ushort_t* __restrict__ A, int lda,
    const ushort_t* __restrict__ B, int ldb,
    ushort_t* __restrict__ Cout, int ldc, int Kd)
{
    __shared__ ushort_t As[128 * BK];
    __shared__ ushort_t Bs[128 * BK];
    __shared__ float sepi[4][1024];

    const int tid  = threadIdx.x;
    const int m0   = blockIdx.y * 128;
    const int n0   = blockIdx.x * 128;
    const int wv   = tid >> 6;
    const int lane = tid & 63;
    const int wm   = (wv >> 1) * 64;
    const int wn   = (wv & 1) * 64;
    const int lr   = lane & 15;
    const int quad = lane >> 4;

    f32x4 acc[4][4];
#pragma unroll
    for (int i = 0; i < 4; i++)
#pragma unroll
        for (int j = 0; j < 4; j++) acc[i][j] = f32x4{0.f, 0.f, 0.f, 0.f};

    const int srA = wv * 32 + (lane >> 2);
    const int scA = (lane & 3) * 8;

    for (int k0 = 0; k0 < Kd; k0 += BK) {
        ll16(A + (size_t)(m0 + srA) * lda + k0 + scA,      &As[wv * 1024]);
        ll16(A + (size_t)(m0 + srA + 16) * lda + k0 + scA, &As[wv * 1024 + 512]);
        ll16(B + (size_t)(n0 + srA) * ldb + k0 + scA,      &Bs[wv * 1024]);
        ll16(B + (size_t)(n0 + srA + 16) * ldb + k0 + scA, &Bs[wv * 1024 + 512]);
        __syncthreads();

        short8 af[4], bf[4];
#pragma unroll
        for (int i = 0; i < 4; i++)
            af[i] = *(const short8*)(&As[(wm + i * 16 + lr) * BK + quad * 8]);
#pragma unroll
        for (int j = 0; j < 4; j++)
            bf[j] = *(const short8*)(&Bs[(wn + j * 16 + lr) * BK + quad * 8]);
#pragma unroll
        for (int i = 0; i < 4; i++)
#pragma unroll
            for (int j = 0; j < 4; j++)
                acc[i][j] = __builtin_amdgcn_mfma_f32_16x16x32_bf16(af[i], bf[j], acc[i][j], 0, 0, 0);
        __syncthreads();
    }

#pragma unroll
    for (int g = 0; g < 4; g++)
        epi_wave_b16(sepi[wv], acc[g],
                     Cout + (size_t)(m0 + wm + g * 16) * ldc + n0 + wn, ldc, lane);
}

// ---------------------------------------------------------------------------
// G4: out = y @ W_out^T (2048 x 1024, K=2048), fp32 out, BM=64 variant.
// ---------------------------------------------------------------------------
__global__ __launch_bounds__(256) void gemm_g4(
    const ushort_t* __restrict__ A, int lda,
    const ushort_t* __restrict__ B, int ldb,
    float* __restrict__ Cout, int ldc, int Kd)
{
    __shared__ ushort_t As[64 * BK];
    __shared__ ushort_t Bs[128 * BK];
    __shared__ float sepi[4][1024];

    const int tid  = threadIdx.x;
    const int m0   = blockIdx.y * 64;
    const int n0   = blockIdx.x * 128;
    const int wv   = tid >> 6;
    const int lane = tid & 63;
    const int wm   = (wv >> 1) * 32;
    const int wn   = (wv & 1) * 64;
    const int lr   = lane & 15;
    const int quad = lane >> 4;

    f32x4 acc[2][4];
#pragma unroll
    for (int i = 0; i < 2; i++)
#pragma unroll
        for (int j = 0; j < 4; j++) acc[i][j] = f32x4{0.f, 0.f, 0.f, 0.f};

    const int srA = wv * 16 + (lane >> 2);
    const int srB = wv * 32 + (lane >> 2);
    const int sc  = (lane & 3) * 8;

    for (int k0 = 0; k0 < Kd; k0 += BK) {
        ll16(A + (size_t)(m0 + srA) * lda + k0 + sc,      &As[wv * 512]);
        ll16(B + (size_t)(n0 + srB) * ldb + k0 + sc,      &Bs[wv * 1024]);
        ll16(B + (size_t)(n0 + srB + 16) * ldb + k0 + sc, &Bs[wv * 1024 + 512]);
        __syncthreads();

        short8 af[2], bf[4];
#pragma unroll
        for (int i = 0; i < 2; i++)
            af[i] = *(const short8*)(&As[(wm + i * 16 + lr) * BK + quad * 8]);
#pragma unroll
        for (int j = 0; j < 4; j++)
            bf[j] = *(const short8*)(&Bs[(wn + j * 16 + lr) * BK + quad * 8]);
#pragma unroll
        for (int i = 0; i < 2; i++)
#pragma unroll
            for (int j = 0; j < 4; j++)
                acc[i][j] = __builtin_amdgcn_mfma_f32_16x16x32_bf16(af[i], bf[j], acc[i][j], 0, 0, 0);
        __syncthreads();
    }

#pragma unroll
    for (int g = 0; g < 2; g++)
        epi_wave_f32(sepi[wv], acc[g],
                     Cout + (size_t)(m0 + wm + g * 16) * ldc + n0 + wn, ldc, lane);
}

// ---------------------------------------------------------------------------
// G2: dbc partials. grid (SK=8, M/128=16, br=2). N=96, guarded coalesced epi.
// ---------------------------------------------------------------------------
__global__ __launch_bounds__(256) void gemm_g2(
    const ushort_t* __restrict__ xc, const ushort_t* __restrict__ wx,
    float* __restrict__ part)
{
    __shared__ ushort_t As[128 * BK];
    __shared__ ushort_t Bs[128 * BK];
    __shared__ float sepi[4][1024];

    const int sk = blockIdx.x, mb = blockIdx.y, br = blockIdx.z;
    const ushort_t* A = xc + (size_t)br * 2048 * 2048;
    const ushort_t* B = wx + (size_t)br * 96 * 2048;
    float* C = part + (size_t)(sk * 2 + br) * 2048 * 96;
    const int m0 = mb * 128;
    const int kb = sk * 256;

    const int tid  = threadIdx.x;
    const int wv   = tid >> 6;
    const int lane = tid & 63;
    const int wm   = (wv >> 1) * 64;
    const int wn   = (wv & 1) * 64;
    const int lr   = lane & 15;
    const int quad = lane >> 4;

    f32x4 acc[4][4];
#pragma unroll
    for (int i = 0; i < 4; i++)
#pragma unroll
        for (int j = 0; j < 4; j++) acc[i][j] = f32x4{0.f, 0.f, 0.f, 0.f};

    const int srA = wv * 32 + (lane >> 2);
    const int sc  = (lane & 3) * 8;

    for (int k0 = kb; k0 < kb + 256; k0 += BK) {
        ll16(A + (size_t)(m0 + srA) * 2048 + k0 + sc,      &As[wv * 1024]);
        ll16(A + (size_t)(m0 + srA + 16) * 2048 + k0 + sc, &As[wv * 1024 + 512]);
        ll16(B + (size_t)(srA) * 2048 + k0 + sc,           &Bs[wv * 1024]);
        ll16(B + (size_t)(srA + 16) * 2048 + k0 + sc,      &Bs[wv * 1024 + 512]);
        __syncthreads();

        short8 af[4], bf[4];
#pragma unroll
        for (int i = 0; i < 4; i++)
            af[i] = *(const short8*)(&As[(wm + i * 16 + lr) * BK + quad * 8]);
#pragma unroll
        for (int j = 0; j < 4; j++)
            bf[j] = *(const short8*)(&Bs[(wn + j * 16 + lr) * BK + quad * 8]);
#pragma unroll
        for (int i = 0; i < 4; i++)
#pragma unroll
            for (int j = 0; j < 4; j++)
                acc[i][j] = __builtin_amdgcn_mfma_f32_16x16x32_bf16(af[i], bf[j], acc[i][j], 0, 0, 0);
        __syncthreads();
    }

    float* sw = sepi[wv];
#pragma unroll
    for (int g = 0; g < 4; g++) {
#pragma unroll
        for (int j = 0; j < 4; j++)
#pragma unroll
            for (int r = 0; r < 4; r++)
                sw[(quad * 4 + r) * 64 + j * 16 + lr] = acc[g][j][r];
        __asm__ volatile("s_waitcnt lgkmcnt(0)" ::: "memory");
        int col = wn + lr * 4;
#pragma unroll
        for (int t = 0; t < 4; t++) {
            int row = t * 4 + quad;
            if (col < 96) {
                float4 v = *(const float4*)(&sw[row * 64 + lr * 4]);
                *(float4*)(C + (size_t)(m0 + wm + g * 16 + row) * 96 + col) = v;
            }
        }
    }
}

__global__ __launch_bounds__(256) void reduce_dbc(
    const float4* __restrict__ part, ushort4* __restrict__ dbc16)
{
    int g = blockIdx.x * 256 + threadIdx.x;   // 98304 total
    const int S = 2 * 2048 * 96 / 4;
    float4 r = part[g];
#pragma unroll
    for (int i = 1; i < 8; i++) {
        float4 p = part[g + i * S];
        r.x += p.x; r.y += p.y; r.z += p.z; r.w += p.w;
    }
    ushort4 o; o.x = f2b(r.x); o.y = f2b(r.y); o.z = f2b(r.z); o.w = f2b(r.w);
    dbc16[g] = o;
}

// ---------------------------------------------------------------------------
// G3: delta16 = softplus(dbc[:, :64] @ Wdt^T + b_dt), bf16 out, fast softplus.
// ---------------------------------------------------------------------------
__global__ __launch_bounds__(256) void gemm_g3(
    const ushort_t* __restrict__ dbc16, const ushort_t* __restrict__ wdt,
    ushort_t* __restrict__ delta,
    const float* __restrict__ bdt_f, const float* __restrict__ bdt_b)
{
    __shared__ ushort_t As[128 * BK];
    __shared__ ushort_t Bs[128 * BK];
    __shared__ float sepi[4][1024];

    const int br = blockIdx.z;
    const ushort_t* A = dbc16 + (size_t)br * 2048 * 96;
    const ushort_t* B = wdt + (size_t)br * 2048 * 64;
    ushort_t* C = delta + (size_t)br * 2048 * 2048;
    const float* bias = br ? bdt_b : bdt_f;

    const int tid  = threadIdx.x;
    const int m0   = blockIdx.y * 128;
    const int n0   = blockIdx.x * 128;
    const int wv   = tid >> 6;
    const int lane = tid & 63;
    const int wm   = (wv >> 1) * 64;
    const int wn   = (wv & 1) * 64;
    const int lr   = lane & 15;
    const int quad = lane >> 4;

    f32x4 acc[4][4];
#pragma unroll
    for (int i = 0; i < 4; i++)
#pragma unroll
        for (int j = 0; j < 4; j++) acc[i][j] = f32x4{0.f, 0.f, 0.f, 0.f};

    const int srA = wv * 32 + (lane >> 2);
    const int sc  = (lane & 3) * 8;

    for (int k0 = 0; k0 < 64; k0 += BK) {
        ll16(A + (size_t)(m0 + srA) * 96 + k0 + sc,       &As[wv * 1024]);
        ll16(A + (size_t)(m0 + srA + 16) * 96 + k0 + sc,  &As[wv * 1024 + 512]);
        ll16(B + (size_t)(n0 + srA) * 64 + k0 + sc,       &Bs[wv * 1024]);
        ll16(B + (size_t)(n0 + srA + 16) * 64 + k0 + sc,  &Bs[wv * 1024 + 512]);
        __syncthreads();

        short8 af[4], bf[4];
#pragma unroll
        for (int i = 0; i < 4; i++)
            af[i] = *(const short8*)(&As[(wm + i * 16 + lr) * BK + quad * 8]);
#pragma unroll
        for (int j = 0; j < 4; j++)
            bf[j] = *(const short8*)(&Bs[(wn + j * 16 + lr) * BK + quad * 8]);
#pragma unroll
        for (int i = 0; i < 4; i++)
#pragma unroll
            for (int j = 0; j < 4; j++)
                acc[i][j] = __builtin_amdgcn_mfma_f32_16x16x32_bf16(af[i], bf[j], acc[i][j], 0, 0, 0);
        __syncthreads();
    }

    float bn[4];
#pragma unroll
    for (int j = 0; j < 4; j++) bn[j] = bias[n0 + wn + j * 16 + lr];
#pragma unroll
    for (int g = 0; g < 4; g++)
#pragma unroll
        for (int j = 0; j < 4; j++)
#pragma unroll
            for (int r = 0; r < 4; r++) {
                float x = acc[g][j][r] + bn[j];
                float sp = fmaxf(x, 0.f) + __logf(1.f + __expf(-fabsf(x)));
                acc[g][j][r] = sp;
            }

#pragma unroll
    for (int g = 0; g < 4; g++)
        epi_wave_b16(sepi[wv], acc[g],
                     C + (size_t)(m0 + wm + g * 16) * 2048 + n0 + wn, 2048, lane);
}

// ---------------------------------------------------------------------------
// Causal depthwise conv (K=4) + bias + silu, both branches, bf16 in/out.
// ---------------------------------------------------------------------------
__global__ __launch_bounds__(256) void conv_silu_kernel(
    const ushort_t* __restrict__ xz,
    const float* __restrict__ w_f, const float* __restrict__ cb_f,
    const float* __restrict__ w_b, const float* __restrict__ cb_b,
    ushort_t* __restrict__ xc16)
{
    int g = blockIdx.x * 256 + threadIdx.x;
    int e  = g & 2047;
    int t  = (g >> 11) & 511;
    int b  = (g >> 20) & 3;
    int br = g >> 22;

    const float* w  = br ? w_b  : w_f;
    const float* cb = br ? cb_b : cb_f;

    float acc = cb[e];
    float4 wv = *(const float4*)(w + e * 4);
    float wk[4] = { wv.x, wv.y, wv.z, wv.w };

#pragma unroll
    for (int k = 0; k < 4; k++) {
        int tp = t - 3 + k;
        if (tp >= 0) {
            int row = br ? (511 - tp) : tp;
            acc += wk[k] * b2f(xz[((size_t)(b * 512 + row)) * 4096 + e]);
        }
    }
    float s = acc / (1.f + __expf(-acc));
    xc16[g] = f2b(s);
}

// ---------------------------------------------------------------------------
// Selective scan v7: one barrier per chunk (sy ping-pong + deferred flush),
// fp32 B/C staging, exp2 with pre-scaled A, z prefetch. 512 blocks, 2 st/thr.
// ---------------------------------------------------------------------------
__global__ __launch_bounds__(256) void scan_kernel(
    const ushort_t* __restrict__ delta,   // [2][B][L][ED] bf16
    const ushort_t* __restrict__ xc,      // [2][B][L][ED] bf16
    const ushort_t* __restrict__ dbc16,   // [2][B][L][96] bf16
    const ushort_t* __restrict__ xz,      // [B][L][4096] bf16 (z half)
    const float* __restrict__ Alog_f, const float* __restrict__ Alog_b,
    const float* __restrict__ Dp_f,   const float* __restrict__ Dp_b,
    ushort_t* __restrict__ yf, ushort_t* __restrict__ yb)
{
    const int blk = blockIdx.x;            // 0..511
    const int eg = blk & 63;
    const int b  = (blk >> 6) & 3;
    const int br = blk >> 8;
    const int e0 = eg * 32;

    const int tid = threadIdx.x;
    const int n2  = tid & 7;
    const int el  = tid >> 3;              // 0..31
    const int e   = e0 + el;

    const float* Alog = br ? Alog_b : Alog_f;
    const float* Dpp  = br ? Dp_b   : Dp_f;
    // pre-scaled by log2(e) so dA = exp2(d * A0)
    const float A0 = -__expf(Alog[e * 16 + n2]) * 1.44269504f;
    const float A1 = -__expf(Alog[e * 16 + n2 + 8]) * 1.44269504f;

    size_t tb = ((size_t)br * 4 + b) * 512;
    const ushort_t* dlt  = delta + tb * 2048;
    const ushort_t* xcb  = xc    + tb * 2048;
    const ushort_t* dbcb = dbc16 + tb * 96;
    ushort_t* y = (br ? yb : yf) + (size_t)b * 512 * 2048;

    __shared__ float    sd[2][32][68];     // d[e][t^swz]
    __shared__ ushort_t sx[2][32][72];     // x[e][t^swz]
    __shared__ float    sB[2][16][68];     // B[n][t^swz] fp32
    __shared__ float    sC[2][16][68];     // C[n][t^swz] fp32
    __shared__ float    sy[2][64][36];     // y[t][e], ping-pong

    const int stt = tid >> 2;              // 0..63 (t within chunk)
    const int seg = tid & 3;               // 8-elem column group
    const int swz = seg * 8;
    const int scol = stt ^ swz;

    float4 rD0 = *(const float4*)(Dpp + e0 + seg * 8);
    float4 rD1 = *(const float4*)(Dpp + e0 + seg * 8 + 4);

    uint4 rdx, rx, rbc, rz;
    uint4 rx_c, rx_f, rz_c, rz_f;

    auto load_regs = [&](int c) {
        int t0 = c * 64;
        rdx = *(const uint4*)(dlt + (size_t)(t0 + stt) * 2048 + e0 + seg * 8);
        rx  = *(const uint4*)(xcb + (size_t)(t0 + stt) * 2048 + e0 + seg * 8);
        rbc = *(const uint4*)(dbcb + (size_t)(t0 + stt) * 96 + 64 + seg * 8);
        int orow = br ? (511 - (t0 + stt)) : (t0 + stt);
        rz  = *(const uint4*)(xz + ((size_t)(b * 512 + orow)) * 4096 + 2048 + e0 + seg * 8);
    };
    auto write_lds = [&](int buf) {
        const uint32_t dw[4] = { rdx.x, rdx.y, rdx.z, rdx.w };
#pragma unroll
        for (int k = 0; k < 4; k++) {
            sd[buf][seg * 8 + 2 * k][scol]     = b2f((ushort_t)(dw[k] & 0xffff));
            sd[buf][seg * 8 + 2 * k + 1][scol] = b2f((ushort_t)(dw[k] >> 16));
        }
        const uint32_t xw[4] = { rx.x, rx.y, rx.z, rx.w };
#pragma unroll
        for (int k = 0; k < 4; k++) {
            sx[buf][seg * 8 + 2 * k][scol]     = (ushort_t)(xw[k] & 0xffff);
            sx[buf][seg * 8 + 2 * k + 1][scol] = (ushort_t)(xw[k] >> 16);
        }
        float* arr = (seg < 2) ? &sB[buf][0][0] : &sC[buf][0][0];
        const int rbase = (seg & 1) * 8;
        const uint32_t bw[4] = { rbc.x, rbc.y, rbc.z, rbc.w };
#pragma unroll
        for (int k = 0; k < 4; k++) {
            arr[(rbase + 2 * k) * 68 + scol]     = b2f((ushort_t)(bw[k] & 0xffff));
            arr[(rbase + 2 * k + 1) * 68 + scol] = b2f((ushort_t)(bw[k] >> 16));
        }
    };
    auto flush = [&](int cm1) {
        const int bufm1 = cm1 & 1;
        int row = cm1 * 64 + stt;
        const uint32_t zw[4] = { rz_f.x, rz_f.y, rz_f.z, rz_f.w };
        float zv[8];
#pragma unroll
        for (int k = 0; k < 4; k++) {
            zv[2 * k]     = b2f((ushort_t)(zw[k] & 0xffff));
            zv[2 * k + 1] = b2f((ushort_t)(zw[k] >> 16));
        }
        float4 p0 = *(const float4*)(&sy[bufm1][stt][seg * 8]);
        float4 p1 = *(const float4*)(&sy[bufm1][stt][seg * 8 + 4]);
        const float pv[8] = { p0.x, p0.y, p0.z, p0.w, p1.x, p1.y, p1.z, p1.w };
        const uint32_t xw[4] = { rx_f.x, rx_f.y, rx_f.z, rx_f.w };
        float xvv[8];
#pragma unroll
        for (int k = 0; k < 4; k++) {
            xvv[2 * k]     = b2f((ushort_t)(xw[k] & 0xffff));
            xvv[2 * k + 1] = b2f((ushort_t)(xw[k] >> 16));
        }
        const float Dv[8] = { rD0.x, rD0.y, rD0.z, rD0.w, rD1.x, rD1.y, rD1.z, rD1.w };
        uint32_t op[4];
#pragma unroll
        for (int k = 0; k < 4; k++) {
            float ga = (pv[2 * k]     + Dv[2 * k]     * xvv[2 * k])     *
                       (zv[2 * k]     / (1.f + __expf(-zv[2 * k])));
            float gb = (pv[2 * k + 1] + Dv[2 * k + 1] * xvv[2 * k + 1]) *
                       (zv[2 * k + 1] / (1.f + __expf(-zv[2 * k + 1])));
            op[k] = (uint32_t)f2b(ga) | ((uint32_t)f2b(gb) << 16);
        }
        *(uint4*)(y + (size_t)row * 2048 + e0 + seg * 8) =
            make_uint4(op[0], op[1], op[2], op[3]);
    };

    float h0 = 0.f, h1 = 0.f;
    const int sw = ((el >> 3) & 3) * 8;    // read-side xor (wave-uniform)

    load_regs(0);
    write_lds(0);
    rx_c = rx; rz_c = rz;

    for (int c = 0; c < 8; ++c) {
        if (c < 7) load_regs(c + 1);
        __syncthreads();
        const int buf = c & 1;

#pragma unroll 4
        for (int tq = 0; tq < 64; tq += 4) {
            const int tc = tq ^ sw;
            float4 dv = *(const float4*)(&sd[buf][el][tc]);
            uint2  xv = *(const uint2*)(&sx[buf][el][tc]);
            float4 B0 = *(const float4*)(&sB[buf][n2][tq]);
            float4 B1 = *(const float4*)(&sB[buf][n2 + 8][tq ^ 8]);
            float4 C0 = *(const float4*)(&sC[buf][n2][tq ^ 16]);
            float4 C1 = *(const float4*)(&sC[buf][n2 + 8][tq ^ 24]);

            float x0 = b2f((ushort_t)(xv.x & 0xffff));
            float x1 = b2f((ushort_t)(xv.x >> 16));
            float x2 = b2f((ushort_t)(xv.y & 0xffff));
            float x3 = b2f((ushort_t)(xv.y >> 16));

            float e00 = EXP2(dv.x * A0), e01 = EXP2(dv.y * A0);
            float e02 = EXP2(dv.z * A0), e03 = EXP2(dv.w * A0);
            float e10 = EXP2(dv.x * A1), e11 = EXP2(dv.y * A1);
            float e12 = EXP2(dv.z * A1), e13 = EXP2(dv.w * A1);

            float dx0 = dv.x * x0, dx1 = dv.y * x1;
            float dx2 = dv.z * x2, dx3 = dv.w * x3;

            h0 = e00 * h0 + dx0 * B0.x;  h1 = e10 * h1 + dx0 * B1.x;
            float p0 = h0 * C0.x + h1 * C1.x;
            h0 = e01 * h0 + dx1 * B0.y;  h1 = e11 * h1 + dx1 * B1.y;
            float p1 = h0 * C0.y + h1 * C1.y;
            h0 = e02 * h0 + dx2 * B0.z;  h1 = e12 * h1 + dx2 * B1.z;
            float p2 = h0 * C0.z + h1 * C1.z;
            h0 = e03 * h0 + dx3 * B0.w;  h1 = e13 * h1 + dx3 * B1.w;
            float p3 = h0 * C0.w + h1 * C1.w;

            p0 = dpp_add<DPP_XOR1>(p0); p0 = dpp_add<DPP_XOR2>(p0); p0 = dpp_add<DPP_HMIR>(p0);
            p1 = dpp_add<DPP_XOR1>(p1); p1 = dpp_add<DPP_XOR2>(p1); p1 = dpp_add<DPP_HMIR>(p1);
            p2 = dpp_add<DPP_XOR1>(p2); p2 = dpp_add<DPP_XOR2>(p2); p2 = dpp_add<DPP_HMIR>(p2);
            p3 = dpp_add<DPP_XOR1>(p3); p3 = dpp_add<DPP_XOR2>(p3); p3 = dpp_add<DPP_HMIR>(p3);

            if (n2 == 0) {
                sy[buf][tq + 0][el] = p0;
                sy[buf][tq + 1][el] = p1;
                sy[buf][tq + 2][el] = p2;
                sy[buf][tq + 3][el] = p3;
            }
        }

        if (c > 0) flush(c - 1);

        if (c < 7) {
            write_lds((c + 1) & 1);
            rx_f = rx_c; rz_f = rz_c;
            rx_c = rx;   rz_c = rz;
        } else {
            rx_f = rx_c; rz_f = rz_c;
        }
    }
    __syncthreads();
    flush(7);
}

__global__ __launch_bounds__(256) void combine_kernel(
    const uint2* __restrict__ yf, const uint2* __restrict__ yb,
    uint2* __restrict__ yc)
{
    int g = blockIdx.x * 256 + threadIdx.x;   // 1048576 total
    int e4 = g & 511;
    int t  = (g >> 9) & 511;
    int b  = g >> 18;
    uint2 a = yf[g];
    uint2 c = yb[((size_t)(b * 512 + 511 - t)) * 512 + e4];
    uint2 o;
    o.x = (uint32_t)f2b(0.5f * (b2f((ushort_t)(a.x & 0xffff)) + b2f((ushort_t)(c.x & 0xffff)))) |
          ((uint32_t)f2b(0.5f * (b2f((ushort_t)(a.x >> 16)) + b2f((ushort_t)(c.x >> 16)))) << 16);
    o.y = (uint32_t)f2b(0.5f * (b2f((ushort_t)(a.y & 0xffff)) + b2f((ushort_t)(c.y & 0xffff)))) |
          ((uint32_t)f2b(0.5f * (b2f((ushort_t)(a.y >> 16)) + b2f((ushort_t)(c.y >> 16)))) << 16);
    yc[g] = o;
}

// ---------------------------------------------------------------------------
// Workspace layout (bytes)
// ---------------------------------------------------------------------------
static const size_t TT = 2048;  // B_SZ * L
static const size_t OFF_XZ16  = 0;                          // 16MB
static const size_t OFF_XC16  = OFF_XZ16  + TT*4096*2;      // 16MB
static const size_t OFF_DBC16 = OFF_XC16  + 2*TT*2048*2;    // .75MB
static const size_t OFF_DELTA = OFF_DBC16 + 2*TT*96*2;      // 16MB
static const size_t OFF_YF    = OFF_DELTA + 2*TT*2048*2;    // 8MB
static const size_t OFF_YB    = OFF_YF    + TT*2048*2;      // 8MB
static const size_t OFF_YC16  = OFF_YB    + TT*2048*2;      // 8MB
static const size_t OFF_X16   = OFF_YC16  + TT*2048*2;      // 4MB
static const size_t OFF_WIN16 = OFF_X16   + TT*1024*2;      // 8MB
static const size_t OFF_WX16  = OFF_WIN16 + 4096*1024*2;    // .75MB
static const size_t OFF_WDT16 = OFF_WX16  + 2*96*2048*2;    // .5MB
static const size_t OFF_WOUT16= OFF_WDT16 + 2*2048*64*2;    // 4MB
static const size_t OFF_PART  = OFF_WOUT16+ 1024*2048*2;    // 12.6MB

extern "C" void kernel_launch(void* const* d_in, const int* in_sizes, int n_in,
                              void* d_out, int out_size, void* d_ws, size_t ws_size,
                              hipStream_t stream) {
    const float* x       = (const float*)d_in[0];
    const float* W_in    = (const float*)d_in[1];
    const float* conv_w  = (const float*)d_in[2];
    const float* conv_b  = (const float*)d_in[3];
    const float* Wx      = (const float*)d_in[4];
    const float* Wdt     = (const float*)d_in[5];
    const float* b_dt    = (const float*)d_in[6];
    const float* A_log   = (const float*)d_in[7];
    const float* Dp      = (const float*)d_in[8];
    const float* conv_w_b= (const float*)d_in[9];
    const float* conv_b_b= (const float*)d_in[10];
    const float* Wx_b    = (const float*)d_in[11];
    const float* Wdt_b   = (const float*)d_in[12];
    const float* b_dt_b  = (const float*)d_in[13];
    const float* A_log_b = (const float*)d_in[14];
    const float* Dp_b    = (const float*)d_in[15];
    const float* W_out   = (const float*)d_in[16];
    float* out = (float*)d_out;

    char* ws = (char*)d_ws;
    ushort_t* xz16  = (ushort_t*)(ws + OFF_XZ16);
    ushort_t* xc16  = (ushort_t*)(ws + OFF_XC16);
    ushort_t* dbc16 = (ushort_t*)(ws + OFF_DBC16);
    ushort_t* delta = (ushort_t*)(ws + OFF_DELTA);
    ushort_t* yf    = (ushort_t*)(ws + OFF_YF);
    ushort_t* yb    = (ushort_t*)(ws + OFF_YB);
    ushort_t* yc16  = (ushort_t*)(ws + OFF_YC16);
    ushort_t* x16   = (ushort_t*)(ws + OFF_X16);
    ushort_t* win16 = (ushort_t*)(ws + OFF_WIN16);
    ushort_t* wx16  = (ushort_t*)(ws + OFF_WX16);
    ushort_t* wdt16 = (ushort_t*)(ws + OFF_WDT16);
    ushort_t* wout16= (ushort_t*)(ws + OFF_WOUT16);
    float*    part  = (float*)(ws + OFF_PART);

    dim3 blk(256);

    CastArgs ca;
    const int n4s[7] = {524288, 1048576, 49152, 49152, 32768, 32768, 524288};
    ca.seg[0] = { (const float4*)x,     (ushort4*)x16 };
    ca.seg[1] = { (const float4*)W_in,  (ushort4*)win16 };
    ca.seg[2] = { (const float4*)Wx,    (ushort4*)wx16 };
    ca.seg[3] = { (const float4*)Wx_b,  (ushort4*)(wx16 + 96 * 2048) };
    ca.seg[4] = { (const float4*)Wdt,   (ushort4*)wdt16 };
    ca.seg[5] = { (const float4*)Wdt_b, (ushort4*)(wdt16 + 2048 * 64) };
    ca.seg[6] = { (const float4*)W_out, (ushort4*)wout16 };
    ca.start[0] = 0;
    for (int i = 0; i < 7; i++) ca.start[i + 1] = ca.start[i] + n4s[i];
    cast_multi<<<(ca.start[7] + 255) / 256, blk, 0, stream>>>(ca);

    gemm_g1<<<dim3(32, 16), blk, 0, stream>>>(x16, 1024, win16, 1024, xz16, 4096, 1024);

    conv_silu_kernel<<<32768, blk, 0, stream>>>(xz16, conv_w, conv_b, conv_w_b, conv_b_b, xc16);

    gemm_g2<<<dim3(8, 16, 2), blk, 0, stream>>>(xc16, wx16, part);
    reduce_dbc<<<384, blk, 0, stream>>>((const float4*)part, (ushort4*)dbc16);

    gemm_g3<<<dim3(16, 16, 2), blk, 0, stream>>>(dbc16, wdt16, delta, b_dt, b_dt_b);

    scan_kernel<<<512, blk, 0, stream>>>(delta, xc16, dbc16, xz16, A_log, A_log_b, Dp, Dp_b, yf, yb);

    combine_kernel<<<4096, blk, 0, stream>>>((const uint2*)yf, (const uint2*)yb, (uint2*)yc16);

    gemm_g4<<<dim3(8, 32), blk, 0, stream>>>(yc16, 2048, wout16, 2048, out, 1024, 2048);
}